// Round 3
// baseline (4049.276 us; speedup 1.0000x reference)
//
#include <hip/hip_runtime.h>
#include <hip/hip_bf16.h>
#include <float.h>

#define NPTS    4096
#define NPOINT  1024
#define NSAMPLE 32
#define BATCH   16
#define NTOT    (BATCH * NPOINT * NSAMPLE)   // 524288 gathered pairs
#define INV_NTOT (1.0f / 524288.0f)
#define BN_EPS  1e-5f

// ---------------------------------------------------------------------------
// K0: zero the 512-float stats accumulators (ws is re-poisoned every launch)
// ---------------------------------------------------------------------------
__global__ void init_stats_kernel(float* __restrict__ stats) {
    stats[threadIdx.x] = 0.0f;
}

// ---------------------------------------------------------------------------
// K1: farthest point sampling. One block per batch, 512 threads, 8 pts/thread.
// Matches jnp.argmax tie-break (lowest index) and exact f32 op order.
// ---------------------------------------------------------------------------
__global__ __launch_bounds__(512) void fps_kernel(const float* __restrict__ xyz,
                                                  float* __restrict__ new_xyz) {
#pragma clang fp contract(off)
    const int b = blockIdx.x;
    const int tid = threadIdx.x;
    const float* X = xyz + (size_t)b * NPTS * 3;

    float px[8], py[8], pz[8], dd[8];
#pragma unroll
    for (int k = 0; k < 8; ++k) {
        int i = tid + k * 512;
        px[k] = X[i * 3 + 0];
        py[k] = X[i * 3 + 1];
        pz[k] = X[i * 3 + 2];
        dd[k] = 1e10f;
    }

    __shared__ float cent[3];
    __shared__ float redv[8];
    __shared__ int   redi[8];

    int far = 0;
    for (int it = 0; it < NPOINT; ++it) {
        if ((far & 511) == tid) {
            const int kk = far >> 9;
            float sx = 0.f, sy = 0.f, sz = 0.f;
#pragma unroll
            for (int k = 0; k < 8; ++k)
                if (k == kk) { sx = px[k]; sy = py[k]; sz = pz[k]; }
            cent[0] = sx; cent[1] = sy; cent[2] = sz;
        }
        __syncthreads();
        const float cx = cent[0], cy = cent[1], cz = cent[2];
        if (tid == 0) {
            float* o = new_xyz + ((size_t)b * NPOINT + it) * 3;
            o[0] = cx; o[1] = cy; o[2] = cz;
        }

        float bv = -1.0f; int bi = 0x7fffffff;
#pragma unroll
        for (int k = 0; k < 8; ++k) {
            const float dx = px[k] - cx;
            const float dy = py[k] - cy;
            const float dz = pz[k] - cz;
            const float dist = (dx * dx + dy * dy) + dz * dz;
            const float nd = fminf(dd[k], dist);
            dd[k] = nd;
            const int i = tid + k * 512;
            if (nd > bv || (nd == bv && i < bi)) { bv = nd; bi = i; }
        }
#pragma unroll
        for (int off = 1; off < 64; off <<= 1) {
            const float ov = __shfl_xor(bv, off);
            const int   oi = __shfl_xor(bi, off);
            if (ov > bv || (ov == bv && oi < bi)) { bv = ov; bi = oi; }
        }
        if ((tid & 63) == 0) { redv[tid >> 6] = bv; redi[tid >> 6] = bi; }
        __syncthreads();
        bv = redv[0]; bi = redi[0];
#pragma unroll
        for (int w = 1; w < 8; ++w) {
            const float ov = redv[w]; const int oi = redi[w];
            if (ov > bv || (ov == bv && oi < bi)) { bv = ov; bi = oi; }
        }
        far = bi;
    }
}

// ---------------------------------------------------------------------------
// K2: k-nearest (stable top-32 of d2 ascending, lowest-index tie-break).
// ---------------------------------------------------------------------------
__global__ __launch_bounds__(256) void knn_kernel(const float* __restrict__ xyz,
                                                  const float* __restrict__ new_xyz,
                                                  int* __restrict__ idx) {
#pragma clang fp contract(off)
    const int m = blockIdx.x;
    const int b = blockIdx.y;
    const int tid = threadIdx.x;
    const float* X = xyz + (size_t)b * NPTS * 3;
    const float* c = new_xyz + ((size_t)b * NPOINT + m) * 3;
    const float cx = c[0], cy = c[1], cz = c[2];
    const float sqc = (cx * cx + cy * cy) + cz * cz;

    float d2[16];
#pragma unroll
    for (int k = 0; k < 16; ++k) {
        const int i = tid + k * 256;
        const float x = X[i * 3 + 0];
        const float y = X[i * 3 + 1];
        const float z = X[i * 3 + 2];
        const float sqi = (x * x + y * y) + z * z;
        const float dot = (cx * x + cy * y) + cz * z;
        d2[k] = (sqc + sqi) - 2.0f * dot;
    }

    __shared__ float redv[4];
    __shared__ int   redi[4];
    int* out = idx + ((size_t)b * NPOINT + m) * NSAMPLE;

    for (int j = 0; j < NSAMPLE; ++j) {
        float bv = FLT_MAX; int bi = 0x7fffffff;
#pragma unroll
        for (int k = 0; k < 16; ++k) {
            const int i = tid + k * 256;
            if (d2[k] < bv || (d2[k] == bv && i < bi)) { bv = d2[k]; bi = i; }
        }
#pragma unroll
        for (int off = 1; off < 64; off <<= 1) {
            const float ov = __shfl_xor(bv, off);
            const int   oi = __shfl_xor(bi, off);
            if (ov < bv || (ov == bv && oi < bi)) { bv = ov; bi = oi; }
        }
        if ((tid & 63) == 0) { redv[tid >> 6] = bv; redi[tid >> 6] = bi; }
        __syncthreads();
        bv = redv[0]; bi = redi[0];
#pragma unroll
        for (int w = 1; w < 4; ++w) {
            const float ov = redv[w]; const int oi = redi[w];
            if (ov < bv || (ov == bv && oi < bi)) { bv = ov; bi = oi; }
        }
        if (tid == 0) out[j] = bi;
        {
            const bool own = ((bi & 255) == tid);
            const int kk = bi >> 8;
#pragma unroll
            for (int k = 0; k < 16; ++k)
                d2[k] = (own && k == kk) ? FLT_MAX : d2[k];
        }
        __syncthreads();
    }
}

// ---------------------------------------------------------------------------
// K3: P1[b,i,oc] = sum_ic w0[oc][3+ic] * points[b,i,ic]  (per raw point,
// 16x cheaper than doing it per gathered pair). fp32, 16 MiB.
// ---------------------------------------------------------------------------
__global__ __launch_bounds__(256) void p1_kernel(const float* __restrict__ points,
                                                 const float* __restrict__ w0,
                                                 float* __restrict__ P1) {
    const int tid = threadIdx.x;
    const int ch = tid & 63, pl = tid >> 6;
    __shared__ float wsm[64 * 65];
    __shared__ float inb[4][65];
    for (int t = tid; t < 64 * 64; t += 256)
        wsm[(t >> 6) * 65 + (t & 63)] = w0[(t >> 6) * 67 + 3 + (t & 63)];
    __syncthreads();
    const int base = blockIdx.x * 256;
    for (int t = 0; t < 64; ++t) {
        const int q = base + t * 4 + pl;   // raw point 0..65535
        inb[pl][ch] = points[(size_t)q * 64 + ch];
        __syncthreads();
        float acc = 0.f;
#pragma unroll
        for (int ic = 0; ic < 64; ++ic)
            acc = fmaf(wsm[ch * 65 + ic], inb[pl][ic], acc);
        P1[(size_t)q * 64 + ch] = acc;
        __syncthreads();
    }
}

// z0 for gathered pair: identical op order everywhere it's recomputed.
__device__ __forceinline__ float z0_calc(float p1v, float bb, float wx0, float wx1,
                                         float wx2, float dx, float dy, float dz) {
    return fmaf(wx2, dz, fmaf(wx1, dy, fmaf(wx0, dx, p1v + bb)));
}

// ---------------------------------------------------------------------------
// K4: stats of layer-0 pre-BN output (no store). 256 thr = 64 ch x 4 pairs.
// ---------------------------------------------------------------------------
__global__ __launch_bounds__(256) void stats0_kernel(
        const float* __restrict__ xyz, const float* __restrict__ new_xyz,
        const int* __restrict__ idx, const float* __restrict__ P1,
        const float* __restrict__ w0, const float* __restrict__ b0,
        float* __restrict__ stats_out) {
    const int tid = threadIdx.x;
    const int ch = tid & 63, pl = tid >> 6;
    const float wx0 = w0[ch * 67 + 0], wx1 = w0[ch * 67 + 1], wx2 = w0[ch * 67 + 2];
    const float bb0 = b0[ch];
    __shared__ float dls[4][4];
    __shared__ float red[512];
    float sl = 0.f, sq = 0.f;
    const int base = blockIdx.x * 256;
    for (int t = 0; t < 64; ++t) {
        const int p = base + t * 4 + pl;
        const int i = idx[p];
        const int bm = p >> 5;
        const int b  = bm >> 10;
        if (ch < 3)
            dls[pl][ch] = xyz[(((size_t)(b << 12)) + i) * 3 + ch]
                        - new_xyz[(size_t)bm * 3 + ch];
        __syncthreads();
        const float z = z0_calc(P1[(((size_t)(b << 12)) + i) * 64 + ch], bb0,
                                wx0, wx1, wx2, dls[pl][0], dls[pl][1], dls[pl][2]);
        sl += z; sq += z * z;
        __syncthreads();
    }
    red[tid] = sl; red[256 + tid] = sq;
    __syncthreads();
    if (pl == 0) {
        atomicAdd(&stats_out[ch],
                  red[ch] + red[64 + ch] + red[128 + ch] + red[192 + ch]);
        atomicAdd(&stats_out[64 + ch],
                  red[256 + ch] + red[256 + 64 + ch] + red[256 + 128 + ch] + red[256 + 192 + ch]);
    }
}

// ---------------------------------------------------------------------------
// K5: recompute z0, BN0+ReLU, conv1 -> stats2 (+ optional Z2 bf16 store).
// ---------------------------------------------------------------------------
template<bool STORE>
__global__ __launch_bounds__(256) void conv1_kernel(
        const float* __restrict__ xyz, const float* __restrict__ new_xyz,
        const int* __restrict__ idx, const float* __restrict__ P1,
        const float* __restrict__ w0, const float* __restrict__ b0,
        const float* __restrict__ stats1,
        const float* __restrict__ g0, const float* __restrict__ be0,
        const float* __restrict__ w1, const float* __restrict__ b1,
        __hip_bfloat16* __restrict__ Z2, float* __restrict__ stats_out) {
    const int tid = threadIdx.x;
    const int ch = tid & 63, pl = tid >> 6;
    __shared__ float w1sm[64 * 65];   // stride 65 -> (ch+ic)%32, 2-way max
    __shared__ float inb1[4][65];
    __shared__ float dls[4][4];
    __shared__ float red[512];
    for (int t = tid; t < 64 * 64; t += 256)
        w1sm[(t >> 6) * 65 + (t & 63)] = w1[t];
    const float wx0 = w0[ch * 67 + 0], wx1 = w0[ch * 67 + 1], wx2 = w0[ch * 67 + 2];
    const float bb0 = b0[ch];
    const float mn = stats1[ch] * INV_NTOT;
    const float vr = stats1[64 + ch] * INV_NTOT - mn * mn;
    const float sc0 = g0[ch] * rsqrtf(vr + BN_EPS);
    const float sh0 = be0[ch] - mn * sc0;
    const float bb1 = b1[ch];
    float sl = 0.f, sq = 0.f;
    __syncthreads();

    const int base = blockIdx.x * 256;
    for (int t = 0; t < 64; ++t) {
        const int p = base + t * 4 + pl;
        const int i = idx[p];
        const int bm = p >> 5;
        const int b  = bm >> 10;
        if (ch < 3)
            dls[pl][ch] = xyz[(((size_t)(b << 12)) + i) * 3 + ch]
                        - new_xyz[(size_t)bm * 3 + ch];
        __syncthreads();
        const float z0 = z0_calc(P1[(((size_t)(b << 12)) + i) * 64 + ch], bb0,
                                 wx0, wx1, wx2, dls[pl][0], dls[pl][1], dls[pl][2]);
        inb1[pl][ch] = fmaxf(fmaf(z0, sc0, sh0), 0.f);
        __syncthreads();
        float z1 = bb1;
#pragma unroll
        for (int ic = 0; ic < 64; ++ic)
            z1 = fmaf(w1sm[ch * 65 + ic], inb1[pl][ic], z1);
        if (STORE) Z2[(size_t)p * 64 + ch] = __float2bfloat16(z1);
        sl += z1; sq += z1 * z1;
        __syncthreads();
    }
    red[tid] = sl; red[256 + tid] = sq;
    __syncthreads();
    if (pl == 0) {
        atomicAdd(&stats_out[ch],
                  red[ch] + red[64 + ch] + red[128 + ch] + red[192 + ch]);
        atomicAdd(&stats_out[64 + ch],
                  red[256 + ch] + red[256 + 64 + ch] + red[256 + 128 + ch] + red[256 + 192 + ch]);
    }
}

// ---------------------------------------------------------------------------
// K6/K7: conv2 (64->128). RECOMP: rebuild h2 from P1 (conv0+conv1 in-kernel);
// else read Z2 bf16. FINAL=0: accumulate stats3. FINAL=1: BN2+ReLU+maxpool
// over each 32-sample group (8 whole groups per block) + transposed write.
// ---------------------------------------------------------------------------
template<bool RECOMP, bool FINAL>
__global__ __launch_bounds__(256) void conv2_kernel(
        const float* __restrict__ xyz, const float* __restrict__ new_xyz,
        const int* __restrict__ idx, const float* __restrict__ P1,
        const float* __restrict__ w0, const float* __restrict__ b0,
        const float* __restrict__ stats1,
        const float* __restrict__ g0, const float* __restrict__ be0,
        const float* __restrict__ w1, const float* __restrict__ b1,
        const __hip_bfloat16* __restrict__ Z2,
        const float* __restrict__ stats2,
        const float* __restrict__ g1, const float* __restrict__ be1,
        const float* __restrict__ w2, const float* __restrict__ b2,
        const float* __restrict__ stats3,
        const float* __restrict__ g2, const float* __restrict__ be2,
        float* __restrict__ stats_out, float* __restrict__ outNP) {
    const int tid = threadIdx.x;
    const int ch = tid & 63,  pl = tid >> 6;    // staging / conv1 layout
    const int c2 = tid & 127, p2 = tid >> 7;    // conv2 layout

    __shared__ float w2sm[128 * 65];
    __shared__ float w1sm[RECOMP ? 64 * 65 : 1];
    __shared__ float inb1[RECOMP ? 4 : 1][65];
    __shared__ float inb2[4][65];
    __shared__ float dls[4][4];
    __shared__ float red[FINAL ? 1 : 512];
    __shared__ float pmax[FINAL ? 2 : 1][128];
    __shared__ float poolbuf[FINAL ? 8 : 1][129];

    for (int t = tid; t < 128 * 64; t += 256)
        w2sm[(t >> 6) * 65 + (t & 63)] = w2[t];
    if (RECOMP)
        for (int t = tid; t < 64 * 64; t += 256)
            w1sm[(t >> 6) * 65 + (t & 63)] = w1[t];

    float wx0 = 0.f, wx1 = 0.f, wx2 = 0.f, bb0 = 0.f, sc0 = 0.f, sh0 = 0.f, bb1 = 0.f;
    if (RECOMP) {
        wx0 = w0[ch * 67 + 0]; wx1 = w0[ch * 67 + 1]; wx2 = w0[ch * 67 + 2];
        bb0 = b0[ch];
        const float mn = stats1[ch] * INV_NTOT;
        const float vr = stats1[64 + ch] * INV_NTOT - mn * mn;
        sc0 = g0[ch] * rsqrtf(vr + BN_EPS);
        sh0 = be0[ch] - mn * sc0;
        bb1 = b1[ch];
    }
    float sc1, sh1;
    {
        const float mn = stats2[ch] * INV_NTOT;
        const float vr = stats2[64 + ch] * INV_NTOT - mn * mn;
        sc1 = g1[ch] * rsqrtf(vr + BN_EPS);
        sh1 = be1[ch] - mn * sc1;
    }
    const float bb2 = b2[c2];
    float sc2 = 0.f, sh2 = 0.f;
    if (FINAL) {
        const float mn = stats3[c2] * INV_NTOT;
        const float vr = stats3[128 + c2] * INV_NTOT - mn * mn;
        sc2 = g2[c2] * rsqrtf(vr + BN_EPS);
        sh2 = be2[c2] - mn * sc2;
    }
    float sl = 0.f, sq = 0.f, mx = -FLT_MAX;
    __syncthreads();

    const int base = blockIdx.x * 256;
    for (int t = 0; t < 64; ++t) {
        const int p = base + t * 4 + pl;
        if (RECOMP) {
            const int i = idx[p];
            const int bm = p >> 5;
            const int b  = bm >> 10;
            if (ch < 3)
                dls[pl][ch] = xyz[(((size_t)(b << 12)) + i) * 3 + ch]
                            - new_xyz[(size_t)bm * 3 + ch];
            __syncthreads();
            const float z0 = z0_calc(P1[(((size_t)(b << 12)) + i) * 64 + ch], bb0,
                                     wx0, wx1, wx2, dls[pl][0], dls[pl][1], dls[pl][2]);
            inb1[pl][ch] = fmaxf(fmaf(z0, sc0, sh0), 0.f);
            __syncthreads();
            float z1 = bb1;
#pragma unroll
            for (int ic = 0; ic < 64; ++ic)
                z1 = fmaf(w1sm[ch * 65 + ic], inb1[pl][ic], z1);
            inb2[pl][ch] = fmaxf(fmaf(z1, sc1, sh1), 0.f);
        } else {
            const float z1 = __bfloat162float(Z2[(size_t)p * 64 + ch]);
            inb2[pl][ch] = fmaxf(fmaf(z1, sc1, sh1), 0.f);
        }
        __syncthreads();

#pragma unroll
        for (int q = 0; q < 2; ++q) {
            const int pr = q * 2 + p2;
            float z2 = bb2;
#pragma unroll
            for (int ic = 0; ic < 64; ++ic)
                z2 = fmaf(w2sm[c2 * 65 + ic], inb2[pr][ic], z2);
            if (FINAL) {
                mx = fmaxf(mx, fmaxf(fmaf(z2, sc2, sh2), 0.f));
            } else {
                sl += z2; sq += z2 * z2;
            }
        }
        if (FINAL && ((t & 7) == 7)) {      // group of 32 samples complete
            pmax[p2][c2] = mx;
            __syncthreads();
            if (p2 == 0)
                poolbuf[t >> 3][c2] = fmaxf(pmax[0][c2], pmax[1][c2]);
            mx = -FLT_MAX;
        }
        __syncthreads();
    }

    if (FINAL) {
        const int b  = base >> 15;
        const int m0 = (base >> 5) & 1023;   // 8 consecutive centroids
#pragma unroll
        for (int r = 0; r < 4; ++r) {
            const int o   = r * 256 + tid;
            const int row = o >> 3;
            const int gg  = o & 7;
            outNP[((size_t)(b * 128 + row)) * 1024 + m0 + gg] = poolbuf[gg][row];
        }
    } else {
        red[tid] = sl; red[256 + tid] = sq;
        __syncthreads();
        if (tid < 128) {
            atomicAdd(&stats_out[tid],       red[tid] + red[128 + tid]);
            atomicAdd(&stats_out[128 + tid], red[256 + tid] + red[256 + 128 + tid]);
        }
    }
}

// ---------------------------------------------------------------------------
extern "C" void kernel_launch(void* const* d_in, const int* in_sizes, int n_in,
                              void* d_out, int out_size, void* d_ws, size_t ws_size,
                              hipStream_t stream) {
    const float* xyz    = (const float*)d_in[0];
    const float* points = (const float*)d_in[1];
    const float* w0  = (const float*)d_in[2];
    const float* b0  = (const float*)d_in[3];
    const float* g0  = (const float*)d_in[4];
    const float* be0 = (const float*)d_in[5];
    const float* w1  = (const float*)d_in[6];
    const float* b1  = (const float*)d_in[7];
    const float* g1  = (const float*)d_in[8];
    const float* be1 = (const float*)d_in[9];
    const float* w2  = (const float*)d_in[10];
    const float* b2  = (const float*)d_in[11];
    const float* g2  = (const float*)d_in[12];
    const float* be2 = (const float*)d_in[13];

    float* out        = (float*)d_out;
    float* new_xyz    = out;                              // (16,1024,3)
    float* new_points = out + (size_t)BATCH * NPOINT * 3; // (16,128,1024)

    // workspace layout (lean): idx 2MiB | stats 4KiB | P1 16MiB | [Z2 64MiB]
    char* ws = (char*)d_ws;
    int*   idx   = (int*)ws;
    float* stats = (float*)(ws + (size_t)(2u << 20));
    float* P1    = (float*)(ws + (size_t)(2u << 20) + 4096);
    const size_t offZ2 = (size_t)(2u << 20) + 4096 + (size_t)BATCH * NPTS * 64 * 4;
    __hip_bfloat16* Z2 = (__hip_bfloat16*)(ws + offZ2);
    const bool storeZ2 = ws_size >= offZ2 + (size_t)NTOT * 64 * 2;  // ~82 MiB

    float* stats1 = stats;         // sum[64],  sumsq[64]
    float* stats2 = stats + 128;   // sum[64],  sumsq[64]
    float* stats3 = stats + 256;   // sum[128], sumsq[128]

    init_stats_kernel<<<1, 512, 0, stream>>>(stats);
    p1_kernel<<<BATCH * NPTS / 256, 256, 0, stream>>>(points, w0, P1);
    fps_kernel<<<BATCH, 512, 0, stream>>>(xyz, new_xyz);
    knn_kernel<<<dim3(NPOINT, BATCH), 256, 0, stream>>>(xyz, new_xyz, idx);
    stats0_kernel<<<NTOT / 256, 256, 0, stream>>>(xyz, new_xyz, idx, P1,
                                                  w0, b0, stats1);
    if (storeZ2) {
        conv1_kernel<true><<<NTOT / 256, 256, 0, stream>>>(
            xyz, new_xyz, idx, P1, w0, b0, stats1, g0, be0, w1, b1, Z2, stats2);
        conv2_kernel<false, false><<<NTOT / 256, 256, 0, stream>>>(
            xyz, new_xyz, idx, P1, w0, b0, stats1, g0, be0, w1, b1, Z2,
            stats2, g1, be1, w2, b2, stats3, g2, be2, stats3, new_points);
        conv2_kernel<false, true><<<NTOT / 256, 256, 0, stream>>>(
            xyz, new_xyz, idx, P1, w0, b0, stats1, g0, be0, w1, b1, Z2,
            stats2, g1, be1, w2, b2, stats3, g2, be2, stats3, new_points);
    } else {
        conv1_kernel<false><<<NTOT / 256, 256, 0, stream>>>(
            xyz, new_xyz, idx, P1, w0, b0, stats1, g0, be0, w1, b1, Z2, stats2);
        conv2_kernel<true, false><<<NTOT / 256, 256, 0, stream>>>(
            xyz, new_xyz, idx, P1, w0, b0, stats1, g0, be0, w1, b1, Z2,
            stats2, g1, be1, w2, b2, stats3, g2, be2, stats3, new_points);
        conv2_kernel<true, true><<<NTOT / 256, 256, 0, stream>>>(
            xyz, new_xyz, idx, P1, w0, b0, stats1, g0, be0, w1, b1, Z2,
            stats2, g1, be1, w2, b2, stats3, g2, be2, stats3, new_points);
    }
}

// Round 4
// 2711.169 us; speedup vs baseline: 1.4936x; 1.4936x over previous
//
#include <hip/hip_runtime.h>
#include <hip/hip_bf16.h>
#include <float.h>

#define NPTS    4096
#define NPOINT  1024
#define NSAMPLE 32
#define BATCH   16
#define NTOT    (BATCH * NPOINT * NSAMPLE)   // 524288 gathered pairs
#define INV_NTOT (1.0f / 524288.0f)
#define BN_EPS  1e-5f

// ---------------------------------------------------------------------------
// K0: zero the 512-float stats accumulators (ws is re-poisoned every launch)
// ---------------------------------------------------------------------------
__global__ void init_stats_kernel(float* __restrict__ stats) {
    stats[threadIdx.x] = 0.0f;
}

// ---------------------------------------------------------------------------
// K1: farthest point sampling, latency-optimized.
// One block per batch, 512 threads, 8 pts/thread in registers.
// - full xyz cached in LDS so every thread reads the centroid itself
//   (no publish step, no second barrier)
// - (dist, index) packed into sortable u64: bits(d)<<32 | (4095-i).
//   d >= 0 always, so float bits are order-isomorphic; max key ==
//   (max dist, lowest index) == jnp.argmax tie-break.
// - wred double-buffered by iteration parity -> ONE __syncthreads per iter.
// ---------------------------------------------------------------------------
__global__ __launch_bounds__(512) void fps_kernel(const float* __restrict__ xyz,
                                                  float* __restrict__ new_xyz) {
#pragma clang fp contract(off)
    const int b = blockIdx.x, tid = threadIdx.x;
    const int lane = tid & 63, wave = tid >> 6;
    const float* X = xyz + (size_t)b * NPTS * 3;

    __shared__ float xs[NPTS], ys[NPTS], zs[NPTS];   // 48 KB point cache
    __shared__ float cents[NPOINT * 3];              // 12 KB deferred output
    __shared__ unsigned long long wred[2][8];

    float px[8], py[8], pz[8], dd[8];
#pragma unroll
    for (int k = 0; k < 8; ++k) {
        const int i = tid + k * 512;
        px[k] = X[i * 3 + 0]; py[k] = X[i * 3 + 1]; pz[k] = X[i * 3 + 2];
        dd[k] = 1e10f;
        xs[i] = px[k]; ys[i] = py[k]; zs[i] = pz[k];
    }
    __syncthreads();

    int far = 0;
    for (int it = 0; it < NPOINT; ++it) {
        const float cx = xs[far], cy = ys[far], cz = zs[far];  // LDS broadcast
        if (tid == 0) {
            cents[it * 3 + 0] = cx; cents[it * 3 + 1] = cy; cents[it * 3 + 2] = cz;
        }
        unsigned long long best = 0;
#pragma unroll
        for (int k = 0; k < 8; ++k) {
            const float dx = px[k] - cx, dy = py[k] - cy, dz = pz[k] - cz;
            const float dist = (dx * dx + dy * dy) + dz * dz;
            const float nd = fminf(dd[k], dist);
            dd[k] = nd;
            const unsigned long long kk =
                ((unsigned long long)__float_as_uint(nd) << 32)
                | (unsigned)(4095 - (tid + k * 512));
            best = kk > best ? kk : best;
        }
#pragma unroll
        for (int off = 1; off < 64; off <<= 1) {
            const unsigned long long o = __shfl_xor(best, off);
            best = o > best ? o : best;
        }
        if (lane == 0) wred[it & 1][wave] = best;
        __syncthreads();
        unsigned long long g = wred[it & 1][0];
#pragma unroll
        for (int w = 1; w < 8; ++w) {
            const unsigned long long o = wred[it & 1][w];
            g = o > g ? o : g;
        }
        far = 4095 - (int)(g & 0xFFFFFFFFull);
    }
    __syncthreads();
    for (int t = tid; t < NPOINT * 3; t += 512)
        new_xyz[(size_t)b * NPOINT * 3 + t] = cents[t];
}

// ---------------------------------------------------------------------------
// K2: k-nearest, barrier-free extraction.
// 4 waves/block; wave w owns points [w*1024, w*1024+1024), 16 keys/thread.
// key = sortable_bits(d2)<<32 | i  (min key == smallest d2, tie lowest idx
// == stable lax.top_k). Each wave extracts its sorted top-32 with intra-wave
// shuffles only; one barrier; wave 0 merges 128 candidates -> out[0..31].
// d2 expression/op-order identical to the passing round-3 kernel.
// ---------------------------------------------------------------------------
__global__ __launch_bounds__(256) void knn_kernel(const float* __restrict__ xyz,
                                                  const float* __restrict__ new_xyz,
                                                  int* __restrict__ idx) {
#pragma clang fp contract(off)
    const int m = blockIdx.x, b = blockIdx.y;
    const int tid = threadIdx.x;
    const int lane = tid & 63, wave = tid >> 6;
    const float* X = xyz + (size_t)b * NPTS * 3;
    const float* c = new_xyz + ((size_t)b * NPOINT + m) * 3;
    const float cx = c[0], cy = c[1], cz = c[2];
    const float sqc = (cx * cx + cy * cy) + cz * cz;

    unsigned long long key[16];
#pragma unroll
    for (int k = 0; k < 16; ++k) {
        const int i = wave * 1024 + k * 64 + lane;
        const float x = X[i * 3 + 0];
        const float y = X[i * 3 + 1];
        const float z = X[i * 3 + 2];
        const float sqi = (x * x + y * y) + z * z;
        const float dot = (cx * x + cy * y) + cz * z;
        const float d2 = (sqc + sqi) - 2.0f * dot;
        const unsigned u = __float_as_uint(d2);
        const unsigned s = u ^ (unsigned)(((int)u >> 31) | 0x80000000);
        key[k] = ((unsigned long long)s << 32) | (unsigned)i;
    }

    __shared__ unsigned long long wk[128];

    for (int j = 0; j < NSAMPLE; ++j) {
        unsigned long long best = key[0];
#pragma unroll
        for (int k = 1; k < 16; ++k) best = key[k] < best ? key[k] : best;
#pragma unroll
        for (int off = 1; off < 64; off <<= 1) {
            const unsigned long long o = __shfl_xor(best, off);
            best = o < best ? o : best;
        }
        if (lane == 0) wk[wave * 32 + j] = best;
        // invalidate winner (keys are unique; exact equality identifies owner)
#pragma unroll
        for (int k = 0; k < 16; ++k)
            key[k] = (key[k] == best) ? ~0ull : key[k];
    }
    __syncthreads();

    if (wave == 0) {
        int* out = idx + ((size_t)b * NPOINT + m) * NSAMPLE;
        unsigned long long a = wk[lane], bb = wk[64 + lane];
        for (int j = 0; j < NSAMPLE; ++j) {
            unsigned long long best = a < bb ? a : bb;
#pragma unroll
            for (int off = 1; off < 64; off <<= 1) {
                const unsigned long long o = __shfl_xor(best, off);
                best = o < best ? o : best;
            }
            if (lane == 0) out[j] = (int)(best & 0xFFFFFFFFull);
            a  = (a  == best) ? ~0ull : a;
            bb = (bb == best) ? ~0ull : bb;
        }
    }
}

// ---------------------------------------------------------------------------
// K3: P1[b,i,oc] = sum_ic w0[oc][3+ic] * points[b,i,ic]  (per raw point,
// 16x cheaper than doing it per gathered pair). fp32, 16 MiB.
// ---------------------------------------------------------------------------
__global__ __launch_bounds__(256) void p1_kernel(const float* __restrict__ points,
                                                 const float* __restrict__ w0,
                                                 float* __restrict__ P1) {
    const int tid = threadIdx.x;
    const int ch = tid & 63, pl = tid >> 6;
    __shared__ float wsm[64 * 65];
    __shared__ float inb[4][65];
    for (int t = tid; t < 64 * 64; t += 256)
        wsm[(t >> 6) * 65 + (t & 63)] = w0[(t >> 6) * 67 + 3 + (t & 63)];
    __syncthreads();
    const int base = blockIdx.x * 256;
    for (int t = 0; t < 64; ++t) {
        const int q = base + t * 4 + pl;   // raw point 0..65535
        inb[pl][ch] = points[(size_t)q * 64 + ch];
        __syncthreads();
        float acc = 0.f;
#pragma unroll
        for (int ic = 0; ic < 64; ++ic)
            acc = fmaf(wsm[ch * 65 + ic], inb[pl][ic], acc);
        P1[(size_t)q * 64 + ch] = acc;
        __syncthreads();
    }
}

// z0 for gathered pair: identical op order everywhere it's recomputed.
__device__ __forceinline__ float z0_calc(float p1v, float bb, float wx0, float wx1,
                                         float wx2, float dx, float dy, float dz) {
    return fmaf(wx2, dz, fmaf(wx1, dy, fmaf(wx0, dx, p1v + bb)));
}

// ---------------------------------------------------------------------------
// K4: stats of layer-0 pre-BN output (no store). 256 thr = 64 ch x 4 pairs.
// ---------------------------------------------------------------------------
__global__ __launch_bounds__(256) void stats0_kernel(
        const float* __restrict__ xyz, const float* __restrict__ new_xyz,
        const int* __restrict__ idx, const float* __restrict__ P1,
        const float* __restrict__ w0, const float* __restrict__ b0,
        float* __restrict__ stats_out) {
    const int tid = threadIdx.x;
    const int ch = tid & 63, pl = tid >> 6;
    const float wx0 = w0[ch * 67 + 0], wx1 = w0[ch * 67 + 1], wx2 = w0[ch * 67 + 2];
    const float bb0 = b0[ch];
    __shared__ float dls[4][4];
    __shared__ float red[512];
    float sl = 0.f, sq = 0.f;
    const int base = blockIdx.x * 256;
    for (int t = 0; t < 64; ++t) {
        const int p = base + t * 4 + pl;
        const int i = idx[p];
        const int bm = p >> 5;
        const int b  = bm >> 10;
        if (ch < 3)
            dls[pl][ch] = xyz[(((size_t)(b << 12)) + i) * 3 + ch]
                        - new_xyz[(size_t)bm * 3 + ch];
        __syncthreads();
        const float z = z0_calc(P1[(((size_t)(b << 12)) + i) * 64 + ch], bb0,
                                wx0, wx1, wx2, dls[pl][0], dls[pl][1], dls[pl][2]);
        sl += z; sq += z * z;
        __syncthreads();
    }
    red[tid] = sl; red[256 + tid] = sq;
    __syncthreads();
    if (pl == 0) {
        atomicAdd(&stats_out[ch],
                  red[ch] + red[64 + ch] + red[128 + ch] + red[192 + ch]);
        atomicAdd(&stats_out[64 + ch],
                  red[256 + ch] + red[256 + 64 + ch] + red[256 + 128 + ch] + red[256 + 192 + ch]);
    }
}

// ---------------------------------------------------------------------------
// K5: recompute z0, BN0+ReLU, conv1 -> stats2 (+ optional Z2 bf16 store).
// ---------------------------------------------------------------------------
template<bool STORE>
__global__ __launch_bounds__(256) void conv1_kernel(
        const float* __restrict__ xyz, const float* __restrict__ new_xyz,
        const int* __restrict__ idx, const float* __restrict__ P1,
        const float* __restrict__ w0, const float* __restrict__ b0,
        const float* __restrict__ stats1,
        const float* __restrict__ g0, const float* __restrict__ be0,
        const float* __restrict__ w1, const float* __restrict__ b1,
        __hip_bfloat16* __restrict__ Z2, float* __restrict__ stats_out) {
    const int tid = threadIdx.x;
    const int ch = tid & 63, pl = tid >> 6;
    __shared__ float w1sm[64 * 65];   // stride 65 -> (ch+ic)%32, 2-way max
    __shared__ float inb1[4][65];
    __shared__ float dls[4][4];
    __shared__ float red[512];
    for (int t = tid; t < 64 * 64; t += 256)
        w1sm[(t >> 6) * 65 + (t & 63)] = w1[t];
    const float wx0 = w0[ch * 67 + 0], wx1 = w0[ch * 67 + 1], wx2 = w0[ch * 67 + 2];
    const float bb0 = b0[ch];
    const float mn = stats1[ch] * INV_NTOT;
    const float vr = stats1[64 + ch] * INV_NTOT - mn * mn;
    const float sc0 = g0[ch] * rsqrtf(vr + BN_EPS);
    const float sh0 = be0[ch] - mn * sc0;
    const float bb1 = b1[ch];
    float sl = 0.f, sq = 0.f;
    __syncthreads();

    const int base = blockIdx.x * 256;
    for (int t = 0; t < 64; ++t) {
        const int p = base + t * 4 + pl;
        const int i = idx[p];
        const int bm = p >> 5;
        const int b  = bm >> 10;
        if (ch < 3)
            dls[pl][ch] = xyz[(((size_t)(b << 12)) + i) * 3 + ch]
                        - new_xyz[(size_t)bm * 3 + ch];
        __syncthreads();
        const float z0 = z0_calc(P1[(((size_t)(b << 12)) + i) * 64 + ch], bb0,
                                 wx0, wx1, wx2, dls[pl][0], dls[pl][1], dls[pl][2]);
        inb1[pl][ch] = fmaxf(fmaf(z0, sc0, sh0), 0.f);
        __syncthreads();
        float z1 = bb1;
#pragma unroll
        for (int ic = 0; ic < 64; ++ic)
            z1 = fmaf(w1sm[ch * 65 + ic], inb1[pl][ic], z1);
        if (STORE) Z2[(size_t)p * 64 + ch] = __float2bfloat16(z1);
        sl += z1; sq += z1 * z1;
        __syncthreads();
    }
    red[tid] = sl; red[256 + tid] = sq;
    __syncthreads();
    if (pl == 0) {
        atomicAdd(&stats_out[ch],
                  red[ch] + red[64 + ch] + red[128 + ch] + red[192 + ch]);
        atomicAdd(&stats_out[64 + ch],
                  red[256 + ch] + red[256 + 64 + ch] + red[256 + 128 + ch] + red[256 + 192 + ch]);
    }
}

// ---------------------------------------------------------------------------
// K6/K7: conv2 (64->128). RECOMP: rebuild h2 from P1 (conv0+conv1 in-kernel);
// else read Z2 bf16. FINAL=0: accumulate stats3. FINAL=1: BN2+ReLU+maxpool
// over each 32-sample group (8 whole groups per block) + transposed write.
// ---------------------------------------------------------------------------
template<bool RECOMP, bool FINAL>
__global__ __launch_bounds__(256) void conv2_kernel(
        const float* __restrict__ xyz, const float* __restrict__ new_xyz,
        const int* __restrict__ idx, const float* __restrict__ P1,
        const float* __restrict__ w0, const float* __restrict__ b0,
        const float* __restrict__ stats1,
        const float* __restrict__ g0, const float* __restrict__ be0,
        const float* __restrict__ w1, const float* __restrict__ b1,
        const __hip_bfloat16* __restrict__ Z2,
        const float* __restrict__ stats2,
        const float* __restrict__ g1, const float* __restrict__ be1,
        const float* __restrict__ w2, const float* __restrict__ b2,
        const float* __restrict__ stats3,
        const float* __restrict__ g2, const float* __restrict__ be2,
        float* __restrict__ stats_out, float* __restrict__ outNP) {
    const int tid = threadIdx.x;
    const int ch = tid & 63,  pl = tid >> 6;    // staging / conv1 layout
    const int c2 = tid & 127, p2 = tid >> 7;    // conv2 layout

    __shared__ float w2sm[128 * 65];
    __shared__ float w1sm[RECOMP ? 64 * 65 : 1];
    __shared__ float inb1[RECOMP ? 4 : 1][65];
    __shared__ float inb2[4][65];
    __shared__ float dls[4][4];
    __shared__ float red[FINAL ? 1 : 512];
    __shared__ float pmax[FINAL ? 2 : 1][128];
    __shared__ float poolbuf[FINAL ? 8 : 1][129];

    for (int t = tid; t < 128 * 64; t += 256)
        w2sm[(t >> 6) * 65 + (t & 63)] = w2[t];
    if (RECOMP)
        for (int t = tid; t < 64 * 64; t += 256)
            w1sm[(t >> 6) * 65 + (t & 63)] = w1[t];

    float wx0 = 0.f, wx1 = 0.f, wx2 = 0.f, bb0 = 0.f, sc0 = 0.f, sh0 = 0.f, bb1 = 0.f;
    if (RECOMP) {
        wx0 = w0[ch * 67 + 0]; wx1 = w0[ch * 67 + 1]; wx2 = w0[ch * 67 + 2];
        bb0 = b0[ch];
        const float mn = stats1[ch] * INV_NTOT;
        const float vr = stats1[64 + ch] * INV_NTOT - mn * mn;
        sc0 = g0[ch] * rsqrtf(vr + BN_EPS);
        sh0 = be0[ch] - mn * sc0;
        bb1 = b1[ch];
    }
    float sc1, sh1;
    {
        const float mn = stats2[ch] * INV_NTOT;
        const float vr = stats2[64 + ch] * INV_NTOT - mn * mn;
        sc1 = g1[ch] * rsqrtf(vr + BN_EPS);
        sh1 = be1[ch] - mn * sc1;
    }
    const float bb2 = b2[c2];
    float sc2 = 0.f, sh2 = 0.f;
    if (FINAL) {
        const float mn = stats3[c2] * INV_NTOT;
        const float vr = stats3[128 + c2] * INV_NTOT - mn * mn;
        sc2 = g2[c2] * rsqrtf(vr + BN_EPS);
        sh2 = be2[c2] - mn * sc2;
    }
    float sl = 0.f, sq = 0.f, mx = -FLT_MAX;
    __syncthreads();

    const int base = blockIdx.x * 256;
    for (int t = 0; t < 64; ++t) {
        const int p = base + t * 4 + pl;
        if (RECOMP) {
            const int i = idx[p];
            const int bm = p >> 5;
            const int b  = bm >> 10;
            if (ch < 3)
                dls[pl][ch] = xyz[(((size_t)(b << 12)) + i) * 3 + ch]
                            - new_xyz[(size_t)bm * 3 + ch];
            __syncthreads();
            const float z0 = z0_calc(P1[(((size_t)(b << 12)) + i) * 64 + ch], bb0,
                                     wx0, wx1, wx2, dls[pl][0], dls[pl][1], dls[pl][2]);
            inb1[pl][ch] = fmaxf(fmaf(z0, sc0, sh0), 0.f);
            __syncthreads();
            float z1 = bb1;
#pragma unroll
            for (int ic = 0; ic < 64; ++ic)
                z1 = fmaf(w1sm[ch * 65 + ic], inb1[pl][ic], z1);
            inb2[pl][ch] = fmaxf(fmaf(z1, sc1, sh1), 0.f);
        } else {
            const float z1 = __bfloat162float(Z2[(size_t)p * 64 + ch]);
            inb2[pl][ch] = fmaxf(fmaf(z1, sc1, sh1), 0.f);
        }
        __syncthreads();

#pragma unroll
        for (int q = 0; q < 2; ++q) {
            const int pr = q * 2 + p2;
            float z2 = bb2;
#pragma unroll
            for (int ic = 0; ic < 64; ++ic)
                z2 = fmaf(w2sm[c2 * 65 + ic], inb2[pr][ic], z2);
            if (FINAL) {
                mx = fmaxf(mx, fmaxf(fmaf(z2, sc2, sh2), 0.f));
            } else {
                sl += z2; sq += z2 * z2;
            }
        }
        if (FINAL && ((t & 7) == 7)) {      // group of 32 samples complete
            pmax[p2][c2] = mx;
            __syncthreads();
            if (p2 == 0)
                poolbuf[t >> 3][c2] = fmaxf(pmax[0][c2], pmax[1][c2]);
            mx = -FLT_MAX;
        }
        __syncthreads();
    }

    if (FINAL) {
        const int b  = base >> 15;
        const int m0 = (base >> 5) & 1023;   // 8 consecutive centroids
#pragma unroll
        for (int r = 0; r < 4; ++r) {
            const int o   = r * 256 + tid;
            const int row = o >> 3;
            const int gg  = o & 7;
            outNP[((size_t)(b * 128 + row)) * 1024 + m0 + gg] = poolbuf[gg][row];
        }
    } else {
        red[tid] = sl; red[256 + tid] = sq;
        __syncthreads();
        if (tid < 128) {
            atomicAdd(&stats_out[tid],       red[tid] + red[128 + tid]);
            atomicAdd(&stats_out[128 + tid], red[256 + tid] + red[256 + 128 + tid]);
        }
    }
}

// ---------------------------------------------------------------------------
extern "C" void kernel_launch(void* const* d_in, const int* in_sizes, int n_in,
                              void* d_out, int out_size, void* d_ws, size_t ws_size,
                              hipStream_t stream) {
    const float* xyz    = (const float*)d_in[0];
    const float* points = (const float*)d_in[1];
    const float* w0  = (const float*)d_in[2];
    const float* b0  = (const float*)d_in[3];
    const float* g0  = (const float*)d_in[4];
    const float* be0 = (const float*)d_in[5];
    const float* w1  = (const float*)d_in[6];
    const float* b1  = (const float*)d_in[7];
    const float* g1  = (const float*)d_in[8];
    const float* be1 = (const float*)d_in[9];
    const float* w2  = (const float*)d_in[10];
    const float* b2  = (const float*)d_in[11];
    const float* g2  = (const float*)d_in[12];
    const float* be2 = (const float*)d_in[13];

    float* out        = (float*)d_out;
    float* new_xyz    = out;                              // (16,1024,3)
    float* new_points = out + (size_t)BATCH * NPOINT * 3; // (16,128,1024)

    // workspace layout (lean): idx 2MiB | stats 4KiB | P1 16MiB | [Z2 64MiB]
    char* ws = (char*)d_ws;
    int*   idx   = (int*)ws;
    float* stats = (float*)(ws + (size_t)(2u << 20));
    float* P1    = (float*)(ws + (size_t)(2u << 20) + 4096);
    const size_t offZ2 = (size_t)(2u << 20) + 4096 + (size_t)BATCH * NPTS * 64 * 4;
    __hip_bfloat16* Z2 = (__hip_bfloat16*)(ws + offZ2);
    const bool storeZ2 = ws_size >= offZ2 + (size_t)NTOT * 64 * 2;  // ~82 MiB

    float* stats1 = stats;         // sum[64],  sumsq[64]
    float* stats2 = stats + 128;   // sum[64],  sumsq[64]
    float* stats3 = stats + 256;   // sum[128], sumsq[128]

    init_stats_kernel<<<1, 512, 0, stream>>>(stats);
    p1_kernel<<<BATCH * NPTS / 256, 256, 0, stream>>>(points, w0, P1);
    fps_kernel<<<BATCH, 512, 0, stream>>>(xyz, new_xyz);
    knn_kernel<<<dim3(NPOINT, BATCH), 256, 0, stream>>>(xyz, new_xyz, idx);
    stats0_kernel<<<NTOT / 256, 256, 0, stream>>>(xyz, new_xyz, idx, P1,
                                                  w0, b0, stats1);
    if (storeZ2) {
        conv1_kernel<true><<<NTOT / 256, 256, 0, stream>>>(
            xyz, new_xyz, idx, P1, w0, b0, stats1, g0, be0, w1, b1, Z2, stats2);
        conv2_kernel<false, false><<<NTOT / 256, 256, 0, stream>>>(
            xyz, new_xyz, idx, P1, w0, b0, stats1, g0, be0, w1, b1, Z2,
            stats2, g1, be1, w2, b2, stats3, g2, be2, stats3, new_points);
        conv2_kernel<false, true><<<NTOT / 256, 256, 0, stream>>>(
            xyz, new_xyz, idx, P1, w0, b0, stats1, g0, be0, w1, b1, Z2,
            stats2, g1, be1, w2, b2, stats3, g2, be2, stats3, new_points);
    } else {
        conv1_kernel<false><<<NTOT / 256, 256, 0, stream>>>(
            xyz, new_xyz, idx, P1, w0, b0, stats1, g0, be0, w1, b1, Z2, stats2);
        conv2_kernel<true, false><<<NTOT / 256, 256, 0, stream>>>(
            xyz, new_xyz, idx, P1, w0, b0, stats1, g0, be0, w1, b1, Z2,
            stats2, g1, be1, w2, b2, stats3, g2, be2, stats3, new_points);
        conv2_kernel<true, true><<<NTOT / 256, 256, 0, stream>>>(
            xyz, new_xyz, idx, P1, w0, b0, stats1, g0, be0, w1, b1, Z2,
            stats2, g1, be1, w2, b2, stats3, g2, be2, stats3, new_points);
    }
}

// Round 5
// 2543.580 us; speedup vs baseline: 1.5920x; 1.0659x over previous
//
#include <hip/hip_runtime.h>
#include <hip/hip_bf16.h>
#include <float.h>

#define NPTS    4096
#define NPOINT  1024
#define NSAMPLE 32
#define BATCH   16
#define NTOT    (BATCH * NPOINT * NSAMPLE)   // 524288 gathered pairs
#define INV_NTOT (1.0f / 524288.0f)
#define BN_EPS  1e-5f

// ---------------------------------------------------------------------------
// DPP wave-64 reduction helpers (pure VALU — no LDS-pipe bpermute/swizzle).
// Chain row_shr:1,2,4,8 + row_bcast15 + row_bcast31 reduces into lane 63.
// ---------------------------------------------------------------------------
template<int CTRL, int OLD>
__device__ __forceinline__ unsigned long long dpp_move_u64(unsigned long long v) {
    const int lo = __builtin_amdgcn_update_dpp(OLD, (int)(unsigned)v,        CTRL, 0xF, 0xF, false);
    const int hi = __builtin_amdgcn_update_dpp(OLD, (int)(unsigned)(v >> 32), CTRL, 0xF, 0xF, false);
    return ((unsigned long long)(unsigned)hi << 32) | (unsigned)lo;
}

// max-reduce to lane 63 (identity 0 — keys are non-negative)
__device__ __forceinline__ unsigned long long dpp_max64_to_lane63(unsigned long long v) {
    unsigned long long o;
    o = dpp_move_u64<0x111, 0>(v); v = o > v ? o : v;   // row_shr:1
    o = dpp_move_u64<0x112, 0>(v); v = o > v ? o : v;   // row_shr:2
    o = dpp_move_u64<0x114, 0>(v); v = o > v ? o : v;   // row_shr:4
    o = dpp_move_u64<0x118, 0>(v); v = o > v ? o : v;   // row_shr:8
    o = dpp_move_u64<0x142, 0>(v); v = o > v ? o : v;   // row_bcast:15
    o = dpp_move_u64<0x143, 0>(v); v = o > v ? o : v;   // row_bcast:31
    return v;
}

// min-reduce to lane 63 (identity ~0)
__device__ __forceinline__ unsigned long long dpp_min64_to_lane63(unsigned long long v) {
    unsigned long long o;
    o = dpp_move_u64<0x111, -1>(v); v = o < v ? o : v;
    o = dpp_move_u64<0x112, -1>(v); v = o < v ? o : v;
    o = dpp_move_u64<0x114, -1>(v); v = o < v ? o : v;
    o = dpp_move_u64<0x118, -1>(v); v = o < v ? o : v;
    o = dpp_move_u64<0x142, -1>(v); v = o < v ? o : v;
    o = dpp_move_u64<0x143, -1>(v); v = o < v ? o : v;
    return v;
}

// broadcast lane 63's u64 to all lanes as a wave-uniform value
__device__ __forceinline__ unsigned long long readlane63_u64(unsigned long long v) {
    const unsigned lo = (unsigned)__builtin_amdgcn_readlane((int)(unsigned)v, 63);
    const unsigned hi = (unsigned)__builtin_amdgcn_readlane((int)(unsigned)(v >> 32), 63);
    return ((unsigned long long)hi << 32) | lo;
}

// ---------------------------------------------------------------------------
// K0: zero the 512-float stats accumulators (ws is re-poisoned every launch)
// ---------------------------------------------------------------------------
__global__ void init_stats_kernel(float* __restrict__ stats) {
    stats[threadIdx.x] = 0.0f;
}

// ---------------------------------------------------------------------------
// K1: farthest point sampling, DPP edition.
// One block per batch, 512 threads, 8 pts/thread in registers; full point set
// cached in LDS so every thread reads the centroid directly. One barrier per
// iteration (parity-double-buffered wave slots). Wave reduce = DPP (VALU),
// key = bits(dist)<<32 | (4095-i): max key == (max dist, lowest index)
// == jnp.argmax tie-break.
// ---------------------------------------------------------------------------
__global__ __launch_bounds__(512) void fps_kernel(const float* __restrict__ xyz,
                                                  float* __restrict__ new_xyz) {
#pragma clang fp contract(off)
    const int b = blockIdx.x, tid = threadIdx.x;
    const int lane = tid & 63, wave = tid >> 6;
    const float* X = xyz + (size_t)b * NPTS * 3;
    float* outC = new_xyz + (size_t)b * NPOINT * 3;

    __shared__ float xs[NPTS], ys[NPTS], zs[NPTS];   // 48 KB point cache
    __shared__ unsigned long long wred[2][8];

    float px[8], py[8], pz[8], dd[8];
    unsigned idneg[8];
#pragma unroll
    for (int k = 0; k < 8; ++k) {
        const int i = tid + k * 512;
        px[k] = X[i * 3 + 0]; py[k] = X[i * 3 + 1]; pz[k] = X[i * 3 + 2];
        dd[k] = 1e10f;
        idneg[k] = (unsigned)(4095 - i);
        xs[i] = px[k]; ys[i] = py[k]; zs[i] = pz[k];
    }
    __syncthreads();

    int far = 0;
    for (int it = 0; it < NPOINT; ++it) {
        const float cx = xs[far], cy = ys[far], cz = zs[far];  // LDS broadcast
        if (tid == 0) {
            outC[it * 3 + 0] = cx; outC[it * 3 + 1] = cy; outC[it * 3 + 2] = cz;
        }
        unsigned long long best = 0;
#pragma unroll
        for (int k = 0; k < 8; ++k) {
            const float dx = px[k] - cx, dy = py[k] - cy, dz = pz[k] - cz;
            const float dist = (dx * dx + dy * dy) + dz * dz;
            const float nd = fminf(dd[k], dist);
            dd[k] = nd;
            const unsigned long long kk =
                ((unsigned long long)__float_as_uint(nd) << 32) | idneg[k];
            best = kk > best ? kk : best;
        }
        best = dpp_max64_to_lane63(best);
        if (lane == 63) wred[it & 1][wave] = best;
        __syncthreads();
        unsigned long long g = wred[it & 1][0];
#pragma unroll
        for (int w = 1; w < 8; ++w) {
            const unsigned long long o = wred[it & 1][w];
            g = o > g ? o : g;
        }
        far = 4095 - (int)(g & 0xFFFFFFFFull);
    }
}

// ---------------------------------------------------------------------------
// K2: k-nearest, DPP edition. 4 waves/block; wave w owns 1024 points,
// 16 keys/thread. key = sortable_bits(d2)<<32 | i (min == smallest d2,
// lowest idx tie == stable lax.top_k). Extraction: per-thread min scan +
// DPP min-reduce + readlane broadcast (zero LDS-pipe ops). One barrier;
// wave 0 merges 4x32 candidates. d2 op order identical to round-3 kernel.
// ---------------------------------------------------------------------------
__global__ __launch_bounds__(256) void knn_kernel(const float* __restrict__ xyz,
                                                  const float* __restrict__ new_xyz,
                                                  int* __restrict__ idx) {
#pragma clang fp contract(off)
    const int m = blockIdx.x, b = blockIdx.y;
    const int tid = threadIdx.x;
    const int lane = tid & 63, wave = tid >> 6;
    const float* X = xyz + (size_t)b * NPTS * 3;
    const float* c = new_xyz + ((size_t)b * NPOINT + m) * 3;
    const float cx = c[0], cy = c[1], cz = c[2];
    const float sqc = (cx * cx + cy * cy) + cz * cz;

    unsigned long long key[16];
#pragma unroll
    for (int k = 0; k < 16; ++k) {
        const int i = wave * 1024 + k * 64 + lane;
        const float x = X[i * 3 + 0];
        const float y = X[i * 3 + 1];
        const float z = X[i * 3 + 2];
        const float sqi = (x * x + y * y) + z * z;
        const float dot = (cx * x + cy * y) + cz * z;
        const float d2 = (sqc + sqi) - 2.0f * dot;
        const unsigned u = __float_as_uint(d2);
        const unsigned s = u ^ (unsigned)(((int)u >> 31) | 0x80000000);
        key[k] = ((unsigned long long)s << 32) | (unsigned)i;
    }

    __shared__ unsigned long long wk[128];

    for (int j = 0; j < NSAMPLE; ++j) {
        unsigned long long best = key[0];
#pragma unroll
        for (int k = 1; k < 16; ++k) best = key[k] < best ? key[k] : best;
        best = dpp_min64_to_lane63(best);
        const unsigned long long bestAll = readlane63_u64(best);
        if (lane == 0) wk[wave * 32 + j] = bestAll;
        // invalidate winner (keys unique; equality identifies owner)
#pragma unroll
        for (int k = 0; k < 16; ++k)
            key[k] = (key[k] == bestAll) ? ~0ull : key[k];
    }
    __syncthreads();

    if (wave == 0) {
        int* out = idx + ((size_t)b * NPOINT + m) * NSAMPLE;
        unsigned long long a = wk[lane], bb = wk[64 + lane];
        for (int j = 0; j < NSAMPLE; ++j) {
            unsigned long long best = a < bb ? a : bb;
            best = dpp_min64_to_lane63(best);
            const unsigned long long bestAll = readlane63_u64(best);
            if (lane == 0) out[j] = (int)(bestAll & 0xFFFFFFFFull);
            a  = (a  == bestAll) ? ~0ull : a;
            bb = (bb == bestAll) ? ~0ull : bb;
        }
    }
}

// ---------------------------------------------------------------------------
// K3: P1[b,i,oc] = sum_ic w0[oc][3+ic] * points[b,i,ic]  (per raw point,
// 16x cheaper than doing it per gathered pair). fp32, 16 MiB.
// ---------------------------------------------------------------------------
__global__ __launch_bounds__(256) void p1_kernel(const float* __restrict__ points,
                                                 const float* __restrict__ w0,
                                                 float* __restrict__ P1) {
    const int tid = threadIdx.x;
    const int ch = tid & 63, pl = tid >> 6;
    __shared__ float wsm[64 * 65];
    __shared__ float inb[4][65];
    for (int t = tid; t < 64 * 64; t += 256)
        wsm[(t >> 6) * 65 + (t & 63)] = w0[(t >> 6) * 67 + 3 + (t & 63)];
    __syncthreads();
    const int base = blockIdx.x * 256;
    for (int t = 0; t < 64; ++t) {
        const int q = base + t * 4 + pl;   // raw point 0..65535
        inb[pl][ch] = points[(size_t)q * 64 + ch];
        __syncthreads();
        float acc = 0.f;
#pragma unroll
        for (int ic = 0; ic < 64; ++ic)
            acc = fmaf(wsm[ch * 65 + ic], inb[pl][ic], acc);
        P1[(size_t)q * 64 + ch] = acc;
        __syncthreads();
    }
}

// z0 for gathered pair: identical op order everywhere it's recomputed.
__device__ __forceinline__ float z0_calc(float p1v, float bb, float wx0, float wx1,
                                         float wx2, float dx, float dy, float dz) {
    return fmaf(wx2, dz, fmaf(wx1, dy, fmaf(wx0, dx, p1v + bb)));
}

// ---------------------------------------------------------------------------
// K4: stats of layer-0 pre-BN output (no store). 256 thr = 64 ch x 4 pairs.
// ---------------------------------------------------------------------------
__global__ __launch_bounds__(256) void stats0_kernel(
        const float* __restrict__ xyz, const float* __restrict__ new_xyz,
        const int* __restrict__ idx, const float* __restrict__ P1,
        const float* __restrict__ w0, const float* __restrict__ b0,
        float* __restrict__ stats_out) {
    const int tid = threadIdx.x;
    const int ch = tid & 63, pl = tid >> 6;
    const float wx0 = w0[ch * 67 + 0], wx1 = w0[ch * 67 + 1], wx2 = w0[ch * 67 + 2];
    const float bb0 = b0[ch];
    __shared__ float dls[4][4];
    __shared__ float red[512];
    float sl = 0.f, sq = 0.f;
    const int base = blockIdx.x * 256;
    for (int t = 0; t < 64; ++t) {
        const int p = base + t * 4 + pl;
        const int i = idx[p];
        const int bm = p >> 5;
        const int b  = bm >> 10;
        if (ch < 3)
            dls[pl][ch] = xyz[(((size_t)(b << 12)) + i) * 3 + ch]
                        - new_xyz[(size_t)bm * 3 + ch];
        __syncthreads();
        const float z = z0_calc(P1[(((size_t)(b << 12)) + i) * 64 + ch], bb0,
                                wx0, wx1, wx2, dls[pl][0], dls[pl][1], dls[pl][2]);
        sl += z; sq += z * z;
        __syncthreads();
    }
    red[tid] = sl; red[256 + tid] = sq;
    __syncthreads();
    if (pl == 0) {
        atomicAdd(&stats_out[ch],
                  red[ch] + red[64 + ch] + red[128 + ch] + red[192 + ch]);
        atomicAdd(&stats_out[64 + ch],
                  red[256 + ch] + red[256 + 64 + ch] + red[256 + 128 + ch] + red[256 + 192 + ch]);
    }
}

// ---------------------------------------------------------------------------
// K5: recompute z0, BN0+ReLU, conv1 -> stats2 (+ optional Z2 bf16 store).
// ---------------------------------------------------------------------------
template<bool STORE>
__global__ __launch_bounds__(256) void conv1_kernel(
        const float* __restrict__ xyz, const float* __restrict__ new_xyz,
        const int* __restrict__ idx, const float* __restrict__ P1,
        const float* __restrict__ w0, const float* __restrict__ b0,
        const float* __restrict__ stats1,
        const float* __restrict__ g0, const float* __restrict__ be0,
        const float* __restrict__ w1, const float* __restrict__ b1,
        __hip_bfloat16* __restrict__ Z2, float* __restrict__ stats_out) {
    const int tid = threadIdx.x;
    const int ch = tid & 63, pl = tid >> 6;
    __shared__ float w1sm[64 * 65];   // stride 65 -> (ch+ic)%32, 2-way max
    __shared__ float inb1[4][65];
    __shared__ float dls[4][4];
    __shared__ float red[512];
    for (int t = tid; t < 64 * 64; t += 256)
        w1sm[(t >> 6) * 65 + (t & 63)] = w1[t];
    const float wx0 = w0[ch * 67 + 0], wx1 = w0[ch * 67 + 1], wx2 = w0[ch * 67 + 2];
    const float bb0 = b0[ch];
    const float mn = stats1[ch] * INV_NTOT;
    const float vr = stats1[64 + ch] * INV_NTOT - mn * mn;
    const float sc0 = g0[ch] * rsqrtf(vr + BN_EPS);
    const float sh0 = be0[ch] - mn * sc0;
    const float bb1 = b1[ch];
    float sl = 0.f, sq = 0.f;
    __syncthreads();

    const int base = blockIdx.x * 256;
    for (int t = 0; t < 64; ++t) {
        const int p = base + t * 4 + pl;
        const int i = idx[p];
        const int bm = p >> 5;
        const int b  = bm >> 10;
        if (ch < 3)
            dls[pl][ch] = xyz[(((size_t)(b << 12)) + i) * 3 + ch]
                        - new_xyz[(size_t)bm * 3 + ch];
        __syncthreads();
        const float z0 = z0_calc(P1[(((size_t)(b << 12)) + i) * 64 + ch], bb0,
                                 wx0, wx1, wx2, dls[pl][0], dls[pl][1], dls[pl][2]);
        inb1[pl][ch] = fmaxf(fmaf(z0, sc0, sh0), 0.f);
        __syncthreads();
        float z1 = bb1;
#pragma unroll
        for (int ic = 0; ic < 64; ++ic)
            z1 = fmaf(w1sm[ch * 65 + ic], inb1[pl][ic], z1);
        if (STORE) Z2[(size_t)p * 64 + ch] = __float2bfloat16(z1);
        sl += z1; sq += z1 * z1;
        __syncthreads();
    }
    red[tid] = sl; red[256 + tid] = sq;
    __syncthreads();
    if (pl == 0) {
        atomicAdd(&stats_out[ch],
                  red[ch] + red[64 + ch] + red[128 + ch] + red[192 + ch]);
        atomicAdd(&stats_out[64 + ch],
                  red[256 + ch] + red[256 + 64 + ch] + red[256 + 128 + ch] + red[256 + 192 + ch]);
    }
}

// ---------------------------------------------------------------------------
// K6/K7: conv2 (64->128). RECOMP: rebuild h2 from P1 (conv0+conv1 in-kernel);
// else read Z2 bf16. FINAL=0: accumulate stats3. FINAL=1: BN2+ReLU+maxpool
// over each 32-sample group (8 whole groups per block) + transposed write.
// ---------------------------------------------------------------------------
template<bool RECOMP, bool FINAL>
__global__ __launch_bounds__(256) void conv2_kernel(
        const float* __restrict__ xyz, const float* __restrict__ new_xyz,
        const int* __restrict__ idx, const float* __restrict__ P1,
        const float* __restrict__ w0, const float* __restrict__ b0,
        const float* __restrict__ stats1,
        const float* __restrict__ g0, const float* __restrict__ be0,
        const float* __restrict__ w1, const float* __restrict__ b1,
        const __hip_bfloat16* __restrict__ Z2,
        const float* __restrict__ stats2,
        const float* __restrict__ g1, const float* __restrict__ be1,
        const float* __restrict__ w2, const float* __restrict__ b2,
        const float* __restrict__ stats3,
        const float* __restrict__ g2, const float* __restrict__ be2,
        float* __restrict__ stats_out, float* __restrict__ outNP) {
    const int tid = threadIdx.x;
    const int ch = tid & 63,  pl = tid >> 6;    // staging / conv1 layout
    const int c2 = tid & 127, p2 = tid >> 7;    // conv2 layout

    __shared__ float w2sm[128 * 65];
    __shared__ float w1sm[RECOMP ? 64 * 65 : 1];
    __shared__ float inb1[RECOMP ? 4 : 1][65];
    __shared__ float inb2[4][65];
    __shared__ float dls[4][4];
    __shared__ float red[FINAL ? 1 : 512];
    __shared__ float pmax[FINAL ? 2 : 1][128];
    __shared__ float poolbuf[FINAL ? 8 : 1][129];

    for (int t = tid; t < 128 * 64; t += 256)
        w2sm[(t >> 6) * 65 + (t & 63)] = w2[t];
    if (RECOMP)
        for (int t = tid; t < 64 * 64; t += 256)
            w1sm[(t >> 6) * 65 + (t & 63)] = w1[t];

    float wx0 = 0.f, wx1 = 0.f, wx2 = 0.f, bb0 = 0.f, sc0 = 0.f, sh0 = 0.f, bb1 = 0.f;
    if (RECOMP) {
        wx0 = w0[ch * 67 + 0]; wx1 = w0[ch * 67 + 1]; wx2 = w0[ch * 67 + 2];
        bb0 = b0[ch];
        const float mn = stats1[ch] * INV_NTOT;
        const float vr = stats1[64 + ch] * INV_NTOT - mn * mn;
        sc0 = g0[ch] * rsqrtf(vr + BN_EPS);
        sh0 = be0[ch] - mn * sc0;
        bb1 = b1[ch];
    }
    float sc1, sh1;
    {
        const float mn = stats2[ch] * INV_NTOT;
        const float vr = stats2[64 + ch] * INV_NTOT - mn * mn;
        sc1 = g1[ch] * rsqrtf(vr + BN_EPS);
        sh1 = be1[ch] - mn * sc1;
    }
    const float bb2 = b2[c2];
    float sc2 = 0.f, sh2 = 0.f;
    if (FINAL) {
        const float mn = stats3[c2] * INV_NTOT;
        const float vr = stats3[128 + c2] * INV_NTOT - mn * mn;
        sc2 = g2[c2] * rsqrtf(vr + BN_EPS);
        sh2 = be2[c2] - mn * sc2;
    }
    float sl = 0.f, sq = 0.f, mx = -FLT_MAX;
    __syncthreads();

    const int base = blockIdx.x * 256;
    for (int t = 0; t < 64; ++t) {
        const int p = base + t * 4 + pl;
        if (RECOMP) {
            const int i = idx[p];
            const int bm = p >> 5;
            const int b  = bm >> 10;
            if (ch < 3)
                dls[pl][ch] = xyz[(((size_t)(b << 12)) + i) * 3 + ch]
                            - new_xyz[(size_t)bm * 3 + ch];
            __syncthreads();
            const float z0 = z0_calc(P1[(((size_t)(b << 12)) + i) * 64 + ch], bb0,
                                     wx0, wx1, wx2, dls[pl][0], dls[pl][1], dls[pl][2]);
            inb1[pl][ch] = fmaxf(fmaf(z0, sc0, sh0), 0.f);
            __syncthreads();
            float z1 = bb1;
#pragma unroll
            for (int ic = 0; ic < 64; ++ic)
                z1 = fmaf(w1sm[ch * 65 + ic], inb1[pl][ic], z1);
            inb2[pl][ch] = fmaxf(fmaf(z1, sc1, sh1), 0.f);
        } else {
            const float z1 = __bfloat162float(Z2[(size_t)p * 64 + ch]);
            inb2[pl][ch] = fmaxf(fmaf(z1, sc1, sh1), 0.f);
        }
        __syncthreads();

#pragma unroll
        for (int q = 0; q < 2; ++q) {
            const int pr = q * 2 + p2;
            float z2 = bb2;
#pragma unroll
            for (int ic = 0; ic < 64; ++ic)
                z2 = fmaf(w2sm[c2 * 65 + ic], inb2[pr][ic], z2);
            if (FINAL) {
                mx = fmaxf(mx, fmaxf(fmaf(z2, sc2, sh2), 0.f));
            } else {
                sl += z2; sq += z2 * z2;
            }
        }
        if (FINAL && ((t & 7) == 7)) {      // group of 32 samples complete
            pmax[p2][c2] = mx;
            __syncthreads();
            if (p2 == 0)
                poolbuf[t >> 3][c2] = fmaxf(pmax[0][c2], pmax[1][c2]);
            mx = -FLT_MAX;
        }
        __syncthreads();
    }

    if (FINAL) {
        const int b  = base >> 15;
        const int m0 = (base >> 5) & 1023;   // 8 consecutive centroids
#pragma unroll
        for (int r = 0; r < 4; ++r) {
            const int o   = r * 256 + tid;
            const int row = o >> 3;
            const int gg  = o & 7;
            outNP[((size_t)(b * 128 + row)) * 1024 + m0 + gg] = poolbuf[gg][row];
        }
    } else {
        red[tid] = sl; red[256 + tid] = sq;
        __syncthreads();
        if (tid < 128) {
            atomicAdd(&stats_out[tid],       red[tid] + red[128 + tid]);
            atomicAdd(&stats_out[128 + tid], red[256 + tid] + red[256 + 128 + tid]);
        }
    }
}

// ---------------------------------------------------------------------------
extern "C" void kernel_launch(void* const* d_in, const int* in_sizes, int n_in,
                              void* d_out, int out_size, void* d_ws, size_t ws_size,
                              hipStream_t stream) {
    const float* xyz    = (const float*)d_in[0];
    const float* points = (const float*)d_in[1];
    const float* w0  = (const float*)d_in[2];
    const float* b0  = (const float*)d_in[3];
    const float* g0  = (const float*)d_in[4];
    const float* be0 = (const float*)d_in[5];
    const float* w1  = (const float*)d_in[6];
    const float* b1  = (const float*)d_in[7];
    const float* g1  = (const float*)d_in[8];
    const float* be1 = (const float*)d_in[9];
    const float* w2  = (const float*)d_in[10];
    const float* b2  = (const float*)d_in[11];
    const float* g2  = (const float*)d_in[12];
    const float* be2 = (const float*)d_in[13];

    float* out        = (float*)d_out;
    float* new_xyz    = out;                              // (16,1024,3)
    float* new_points = out + (size_t)BATCH * NPOINT * 3; // (16,128,1024)

    // workspace layout (lean): idx 2MiB | stats 4KiB | P1 16MiB | [Z2 64MiB]
    char* ws = (char*)d_ws;
    int*   idx   = (int*)ws;
    float* stats = (float*)(ws + (size_t)(2u << 20));
    float* P1    = (float*)(ws + (size_t)(2u << 20) + 4096);
    const size_t offZ2 = (size_t)(2u << 20) + 4096 + (size_t)BATCH * NPTS * 64 * 4;
    __hip_bfloat16* Z2 = (__hip_bfloat16*)(ws + offZ2);
    const bool storeZ2 = ws_size >= offZ2 + (size_t)NTOT * 64 * 2;  // ~82 MiB

    float* stats1 = stats;         // sum[64],  sumsq[64]
    float* stats2 = stats + 128;   // sum[64],  sumsq[64]
    float* stats3 = stats + 256;   // sum[128], sumsq[128]

    init_stats_kernel<<<1, 512, 0, stream>>>(stats);
    p1_kernel<<<BATCH * NPTS / 256, 256, 0, stream>>>(points, w0, P1);
    fps_kernel<<<BATCH, 512, 0, stream>>>(xyz, new_xyz);
    knn_kernel<<<dim3(NPOINT, BATCH), 256, 0, stream>>>(xyz, new_xyz, idx);
    stats0_kernel<<<NTOT / 256, 256, 0, stream>>>(xyz, new_xyz, idx, P1,
                                                  w0, b0, stats1);
    if (storeZ2) {
        conv1_kernel<true><<<NTOT / 256, 256, 0, stream>>>(
            xyz, new_xyz, idx, P1, w0, b0, stats1, g0, be0, w1, b1, Z2, stats2);
        conv2_kernel<false, false><<<NTOT / 256, 256, 0, stream>>>(
            xyz, new_xyz, idx, P1, w0, b0, stats1, g0, be0, w1, b1, Z2,
            stats2, g1, be1, w2, b2, stats3, g2, be2, stats3, new_points);
        conv2_kernel<false, true><<<NTOT / 256, 256, 0, stream>>>(
            xyz, new_xyz, idx, P1, w0, b0, stats1, g0, be0, w1, b1, Z2,
            stats2, g1, be1, w2, b2, stats3, g2, be2, stats3, new_points);
    } else {
        conv1_kernel<false><<<NTOT / 256, 256, 0, stream>>>(
            xyz, new_xyz, idx, P1, w0, b0, stats1, g0, be0, w1, b1, Z2, stats2);
        conv2_kernel<true, false><<<NTOT / 256, 256, 0, stream>>>(
            xyz, new_xyz, idx, P1, w0, b0, stats1, g0, be0, w1, b1, Z2,
            stats2, g1, be1, w2, b2, stats3, g2, be2, stats3, new_points);
        conv2_kernel<true, true><<<NTOT / 256, 256, 0, stream>>>(
            xyz, new_xyz, idx, P1, w0, b0, stats1, g0, be0, w1, b1, Z2,
            stats2, g1, be1, w2, b2, stats3, g2, be2, stats3, new_points);
    }
}

// Round 6
// 1999.090 us; speedup vs baseline: 2.0256x; 1.2724x over previous
//
#include <hip/hip_runtime.h>
#include <hip/hip_bf16.h>
#include <float.h>

#define NPTS    4096
#define NPOINT  1024
#define NSAMPLE 32
#define BATCH   16
#define NTOT    (BATCH * NPOINT * NSAMPLE)   // 524288 gathered pairs
#define INV_NTOT (1.0f / 524288.0f)
#define BN_EPS  1e-5f

// ---------------------------------------------------------------------------
// DPP wave-64 reduction helpers (pure VALU — no LDS-pipe bpermute/swizzle).
// ---------------------------------------------------------------------------
template<int CTRL, int OLD>
__device__ __forceinline__ unsigned long long dpp_move_u64(unsigned long long v) {
    const int lo = __builtin_amdgcn_update_dpp(OLD, (int)(unsigned)v,        CTRL, 0xF, 0xF, false);
    const int hi = __builtin_amdgcn_update_dpp(OLD, (int)(unsigned)(v >> 32), CTRL, 0xF, 0xF, false);
    return ((unsigned long long)(unsigned)hi << 32) | (unsigned)lo;
}

__device__ __forceinline__ unsigned long long dpp_max64_to_lane63(unsigned long long v) {
    unsigned long long o;
    o = dpp_move_u64<0x111, 0>(v); v = o > v ? o : v;
    o = dpp_move_u64<0x112, 0>(v); v = o > v ? o : v;
    o = dpp_move_u64<0x114, 0>(v); v = o > v ? o : v;
    o = dpp_move_u64<0x118, 0>(v); v = o > v ? o : v;
    o = dpp_move_u64<0x142, 0>(v); v = o > v ? o : v;
    o = dpp_move_u64<0x143, 0>(v); v = o > v ? o : v;
    return v;
}

__device__ __forceinline__ unsigned long long dpp_min64_to_lane63(unsigned long long v) {
    unsigned long long o;
    o = dpp_move_u64<0x111, -1>(v); v = o < v ? o : v;
    o = dpp_move_u64<0x112, -1>(v); v = o < v ? o : v;
    o = dpp_move_u64<0x114, -1>(v); v = o < v ? o : v;
    o = dpp_move_u64<0x118, -1>(v); v = o < v ? o : v;
    o = dpp_move_u64<0x142, -1>(v); v = o < v ? o : v;
    o = dpp_move_u64<0x143, -1>(v); v = o < v ? o : v;
    return v;
}

__device__ __forceinline__ unsigned long long readlane63_u64(unsigned long long v) {
    const unsigned lo = (unsigned)__builtin_amdgcn_readlane((int)(unsigned)v, 63);
    const unsigned hi = (unsigned)__builtin_amdgcn_readlane((int)(unsigned)(v >> 32), 63);
    return ((unsigned long long)hi << 32) | lo;
}

// ---------------------------------------------------------------------------
__global__ void init_stats_kernel(float* __restrict__ stats) {
    stats[threadIdx.x] = 0.0f;
}

// ---------------------------------------------------------------------------
// K1: FPS. Per-point tracking = (float, u32) with strictly-greater compare
// (first-wins == lowest k == lowest index in-lane); u64 pack only at the
// wave reduce. One barrier/iter, parity-buffered cross-wave slots.
// ---------------------------------------------------------------------------
__global__ __launch_bounds__(512) void fps_kernel(const float* __restrict__ xyz,
                                                  float* __restrict__ new_xyz) {
#pragma clang fp contract(off)
    const int b = blockIdx.x, tid = threadIdx.x;
    const int lane = tid & 63, wave = tid >> 6;
    const float* X = xyz + (size_t)b * NPTS * 3;
    float* outC = new_xyz + (size_t)b * NPOINT * 3;

    __shared__ float xs[NPTS], ys[NPTS], zs[NPTS];
    __shared__ unsigned long long wred[2][8];

    float px[8], py[8], pz[8], dd[8];
    unsigned idneg[8];
#pragma unroll
    for (int k = 0; k < 8; ++k) {
        const int i = tid + k * 512;
        px[k] = X[i * 3 + 0]; py[k] = X[i * 3 + 1]; pz[k] = X[i * 3 + 2];
        dd[k] = 1e10f;
        idneg[k] = (unsigned)(4095 - i);
        xs[i] = px[k]; ys[i] = py[k]; zs[i] = pz[k];
    }
    __syncthreads();

    int far = 0;
    for (int it = 0; it < NPOINT; ++it) {
        const float cx = xs[far], cy = ys[far], cz = zs[far];
        if (tid == 0) {
            outC[it * 3 + 0] = cx; outC[it * 3 + 1] = cy; outC[it * 3 + 2] = cz;
        }
        float bv = -1.0f; unsigned biNeg = 0;
#pragma unroll
        for (int k = 0; k < 8; ++k) {
            const float dx = px[k] - cx, dy = py[k] - cy, dz = pz[k] - cz;
            const float dist = (dx * dx + dy * dy) + dz * dz;
            const float nd = fminf(dd[k], dist);
            dd[k] = nd;
            const bool gt = nd > bv;
            bv = gt ? nd : bv;
            biNeg = gt ? idneg[k] : biNeg;
        }
        unsigned long long best =
            ((unsigned long long)__float_as_uint(bv) << 32) | biNeg;
        best = dpp_max64_to_lane63(best);
        if (lane == 63) wred[it & 1][wave] = best;
        __syncthreads();
        unsigned long long g = wred[it & 1][0];
#pragma unroll
        for (int w = 1; w < 8; ++w) {
            const unsigned long long o = wred[it & 1][w];
            g = o > g ? o : g;
        }
        far = 4095 - (int)(g & 0xFFFFFFFFull);
    }
}

// ---------------------------------------------------------------------------
// K2: k-nearest (unchanged from round 5 — DPP extraction).
// ---------------------------------------------------------------------------
__global__ __launch_bounds__(256) void knn_kernel(const float* __restrict__ xyz,
                                                  const float* __restrict__ new_xyz,
                                                  int* __restrict__ idx) {
#pragma clang fp contract(off)
    const int m = blockIdx.x, b = blockIdx.y;
    const int tid = threadIdx.x;
    const int lane = tid & 63, wave = tid >> 6;
    const float* X = xyz + (size_t)b * NPTS * 3;
    const float* c = new_xyz + ((size_t)b * NPOINT + m) * 3;
    const float cx = c[0], cy = c[1], cz = c[2];
    const float sqc = (cx * cx + cy * cy) + cz * cz;

    unsigned long long key[16];
#pragma unroll
    for (int k = 0; k < 16; ++k) {
        const int i = wave * 1024 + k * 64 + lane;
        const float x = X[i * 3 + 0];
        const float y = X[i * 3 + 1];
        const float z = X[i * 3 + 2];
        const float sqi = (x * x + y * y) + z * z;
        const float dot = (cx * x + cy * y) + cz * z;
        const float d2 = (sqc + sqi) - 2.0f * dot;
        const unsigned u = __float_as_uint(d2);
        const unsigned s = u ^ (unsigned)(((int)u >> 31) | 0x80000000);
        key[k] = ((unsigned long long)s << 32) | (unsigned)i;
    }

    __shared__ unsigned long long wk[128];

    for (int j = 0; j < NSAMPLE; ++j) {
        unsigned long long best = key[0];
#pragma unroll
        for (int k = 1; k < 16; ++k) best = key[k] < best ? key[k] : best;
        best = dpp_min64_to_lane63(best);
        const unsigned long long bestAll = readlane63_u64(best);
        if (lane == 0) wk[wave * 32 + j] = bestAll;
#pragma unroll
        for (int k = 0; k < 16; ++k)
            key[k] = (key[k] == bestAll) ? ~0ull : key[k];
    }
    __syncthreads();

    if (wave == 0) {
        int* out = idx + ((size_t)b * NPOINT + m) * NSAMPLE;
        unsigned long long a = wk[lane], bb = wk[64 + lane];
        for (int j = 0; j < NSAMPLE; ++j) {
            unsigned long long best = a < bb ? a : bb;
            best = dpp_min64_to_lane63(best);
            const unsigned long long bestAll = readlane63_u64(best);
            if (lane == 0) out[j] = (int)(bestAll & 0xFFFFFFFFull);
            a  = (a  == bestAll) ? ~0ull : a;
            bb = (bb == bestAll) ? ~0ull : bb;
        }
    }
}

// ---------------------------------------------------------------------------
// K3: P1 = points @ w0[:,3:]^T per raw point (unchanged).
// ---------------------------------------------------------------------------
__global__ __launch_bounds__(256) void p1_kernel(const float* __restrict__ points,
                                                 const float* __restrict__ w0,
                                                 float* __restrict__ P1) {
    const int tid = threadIdx.x;
    const int ch = tid & 63, pl = tid >> 6;
    __shared__ float wsm[64 * 65];
    __shared__ float inb[4][65];
    for (int t = tid; t < 64 * 64; t += 256)
        wsm[(t >> 6) * 65 + (t & 63)] = w0[(t >> 6) * 67 + 3 + (t & 63)];
    __syncthreads();
    const int base = blockIdx.x * 256;
    for (int t = 0; t < 64; ++t) {
        const int q = base + t * 4 + pl;
        inb[pl][ch] = points[(size_t)q * 64 + ch];
        __syncthreads();
        float acc = 0.f;
#pragma unroll
        for (int ic = 0; ic < 64; ++ic)
            acc = fmaf(wsm[ch * 65 + ic], inb[pl][ic], acc);
        P1[(size_t)q * 64 + ch] = acc;
        __syncthreads();
    }
}

__device__ __forceinline__ float z0_calc(float p1v, float bb, float wx0, float wx1,
                                         float wx2, float dx, float dy, float dz) {
    return fmaf(wx2, dz, fmaf(wx1, dy, fmaf(wx0, dx, p1v + bb)));
}

// ---------------------------------------------------------------------------
// K4: stats of layer-0 pre-BN output (unchanged).
// ---------------------------------------------------------------------------
__global__ __launch_bounds__(256) void stats0_kernel(
        const float* __restrict__ xyz, const float* __restrict__ new_xyz,
        const int* __restrict__ idx, const float* __restrict__ P1,
        const float* __restrict__ w0, const float* __restrict__ b0,
        float* __restrict__ stats_out) {
    const int tid = threadIdx.x;
    const int ch = tid & 63, pl = tid >> 6;
    const float wx0 = w0[ch * 67 + 0], wx1 = w0[ch * 67 + 1], wx2 = w0[ch * 67 + 2];
    const float bb0 = b0[ch];
    __shared__ float dls[4][4];
    __shared__ float red[512];
    float sl = 0.f, sq = 0.f;
    const int base = blockIdx.x * 256;
    for (int t = 0; t < 64; ++t) {
        const int p = base + t * 4 + pl;
        const int i = idx[p];
        const int bm = p >> 5;
        const int b  = bm >> 10;
        if (ch < 3)
            dls[pl][ch] = xyz[(((size_t)(b << 12)) + i) * 3 + ch]
                        - new_xyz[(size_t)bm * 3 + ch];
        __syncthreads();
        const float z = z0_calc(P1[(((size_t)(b << 12)) + i) * 64 + ch], bb0,
                                wx0, wx1, wx2, dls[pl][0], dls[pl][1], dls[pl][2]);
        sl += z; sq += z * z;
        __syncthreads();
    }
    red[tid] = sl; red[256 + tid] = sq;
    __syncthreads();
    if (pl == 0) {
        atomicAdd(&stats_out[ch],
                  red[ch] + red[64 + ch] + red[128 + ch] + red[192 + ch]);
        atomicAdd(&stats_out[64 + ch],
                  red[256 + ch] + red[256 + 64 + ch] + red[256 + 128 + ch] + red[256 + 192 + ch]);
    }
}

// ---------------------------------------------------------------------------
// K5: conv1 with REGISTER weights + float4 broadcast input reads.
// FMA order identical to previous rounds -> bit-identical z1.
// ---------------------------------------------------------------------------
template<bool STORE>
__global__ __launch_bounds__(256) void conv1_kernel(
        const float* __restrict__ xyz, const float* __restrict__ new_xyz,
        const int* __restrict__ idx, const float* __restrict__ P1,
        const float* __restrict__ w0, const float* __restrict__ b0,
        const float* __restrict__ stats1,
        const float* __restrict__ g0, const float* __restrict__ be0,
        const float* __restrict__ w1, const float* __restrict__ b1,
        __hip_bfloat16* __restrict__ Z2, float* __restrict__ stats_out) {
    const int tid = threadIdx.x;
    const int ch = tid & 63, pl = tid >> 6;
    __shared__ float w1ld[64 * 65];
    __shared__ float inb1[4][68];   // stride 68 -> rows 16B-aligned
    __shared__ float dls[4][4];
    __shared__ float red[512];
    for (int t = tid; t < 64 * 64; t += 256)
        w1ld[(t >> 6) * 65 + (t & 63)] = w1[t];
    __syncthreads();
    float wreg[64];
#pragma unroll
    for (int ic = 0; ic < 64; ++ic) wreg[ic] = w1ld[ch * 65 + ic];

    const float wx0 = w0[ch * 67 + 0], wx1 = w0[ch * 67 + 1], wx2 = w0[ch * 67 + 2];
    const float bb0 = b0[ch];
    const float mn = stats1[ch] * INV_NTOT;
    const float vr = stats1[64 + ch] * INV_NTOT - mn * mn;
    const float sc0 = g0[ch] * rsqrtf(vr + BN_EPS);
    const float sh0 = be0[ch] - mn * sc0;
    const float bb1 = b1[ch];
    float sl = 0.f, sq = 0.f;

    const int base = blockIdx.x * 256;
    for (int t = 0; t < 64; ++t) {
        const int p = base + t * 4 + pl;
        const int i = idx[p];
        const int bm = p >> 5;
        const int b  = bm >> 10;
        if (ch < 3)
            dls[pl][ch] = xyz[(((size_t)(b << 12)) + i) * 3 + ch]
                        - new_xyz[(size_t)bm * 3 + ch];
        __syncthreads();
        const float z0 = z0_calc(P1[(((size_t)(b << 12)) + i) * 64 + ch], bb0,
                                 wx0, wx1, wx2, dls[pl][0], dls[pl][1], dls[pl][2]);
        inb1[pl][ch] = fmaxf(fmaf(z0, sc0, sh0), 0.f);
        __syncthreads();
        const float4* row = (const float4*)&inb1[pl][0];
        float z1 = bb1;
#pragma unroll
        for (int ic4 = 0; ic4 < 16; ++ic4) {
            const float4 v = row[ic4];
            z1 = fmaf(wreg[4 * ic4 + 0], v.x, z1);
            z1 = fmaf(wreg[4 * ic4 + 1], v.y, z1);
            z1 = fmaf(wreg[4 * ic4 + 2], v.z, z1);
            z1 = fmaf(wreg[4 * ic4 + 3], v.w, z1);
        }
        if (STORE) Z2[(size_t)p * 64 + ch] = __float2bfloat16(z1);
        sl += z1; sq += z1 * z1;
        __syncthreads();
    }
    red[tid] = sl; red[256 + tid] = sq;
    __syncthreads();
    if (pl == 0) {
        atomicAdd(&stats_out[ch],
                  red[ch] + red[64 + ch] + red[128 + ch] + red[192 + ch]);
        atomicAdd(&stats_out[64 + ch],
                  red[256 + ch] + red[256 + 64 + ch] + red[256 + 128 + ch] + red[256 + 192 + ch]);
    }
}

// ---------------------------------------------------------------------------
// K6: conv2 SINGLE pass: register weights, stats3 + per-group z3 max/min.
// BN2+ReLU+maxpool moved to the epilogue via monotonicity (exact).
// ---------------------------------------------------------------------------
template<bool RECOMP>
__global__ __launch_bounds__(256) void conv2s_kernel(
        const float* __restrict__ xyz, const float* __restrict__ new_xyz,
        const int* __restrict__ idx, const float* __restrict__ P1,
        const float* __restrict__ w0, const float* __restrict__ b0,
        const float* __restrict__ stats1,
        const float* __restrict__ g0, const float* __restrict__ be0,
        const float* __restrict__ w1, const float* __restrict__ b1,
        const __hip_bfloat16* __restrict__ Z2,
        const float* __restrict__ stats2,
        const float* __restrict__ g1, const float* __restrict__ be1,
        const float* __restrict__ w2, const float* __restrict__ b2,
        float* __restrict__ stats_out,
        float* __restrict__ Z3max, float* __restrict__ Z3min) {
    const int tid = threadIdx.x;
    const int ch = tid & 63,  pl = tid >> 6;
    const int c2 = tid & 127, p2 = tid >> 7;

    __shared__ float w2ld[128 * 65];
    __shared__ float w1sm[RECOMP ? 64 * 65 : 1];
    __shared__ float inb1[RECOMP ? 4 : 1][68];
    __shared__ float inb2[4][68];
    __shared__ float dls[4][4];
    __shared__ float red[512];
    __shared__ float pmax[2][128];
    __shared__ float pmin[2][128];

    for (int t = tid; t < 128 * 64; t += 256)
        w2ld[(t >> 6) * 65 + (t & 63)] = w2[t];
    if (RECOMP)
        for (int t = tid; t < 64 * 64; t += 256)
            w1sm[(t >> 6) * 65 + (t & 63)] = w1[t];
    __syncthreads();
    float wreg[64];
#pragma unroll
    for (int ic = 0; ic < 64; ++ic) wreg[ic] = w2ld[c2 * 65 + ic];

    float wx0 = 0.f, wx1 = 0.f, wx2 = 0.f, bb0 = 0.f, sc0 = 0.f, sh0 = 0.f, bb1 = 0.f;
    if (RECOMP) {
        wx0 = w0[ch * 67 + 0]; wx1 = w0[ch * 67 + 1]; wx2 = w0[ch * 67 + 2];
        bb0 = b0[ch];
        const float mn = stats1[ch] * INV_NTOT;
        const float vr = stats1[64 + ch] * INV_NTOT - mn * mn;
        sc0 = g0[ch] * rsqrtf(vr + BN_EPS);
        sh0 = be0[ch] - mn * sc0;
        bb1 = b1[ch];
    }
    float sc1, sh1;
    {
        const float mn = stats2[ch] * INV_NTOT;
        const float vr = stats2[64 + ch] * INV_NTOT - mn * mn;
        sc1 = g1[ch] * rsqrtf(vr + BN_EPS);
        sh1 = be1[ch] - mn * sc1;
    }
    const float bb2 = b2[c2];
    float sl = 0.f, sq = 0.f, mx = -FLT_MAX, mnv = FLT_MAX;

    const int base = blockIdx.x * 256;
    for (int t = 0; t < 64; ++t) {
        const int p = base + t * 4 + pl;
        if (RECOMP) {
            const int i = idx[p];
            const int bm = p >> 5;
            const int b  = bm >> 10;
            if (ch < 3)
                dls[pl][ch] = xyz[(((size_t)(b << 12)) + i) * 3 + ch]
                            - new_xyz[(size_t)bm * 3 + ch];
            __syncthreads();
            const float z0 = z0_calc(P1[(((size_t)(b << 12)) + i) * 64 + ch], bb0,
                                     wx0, wx1, wx2, dls[pl][0], dls[pl][1], dls[pl][2]);
            inb1[pl][ch] = fmaxf(fmaf(z0, sc0, sh0), 0.f);
            __syncthreads();
            const float4* row1 = (const float4*)&inb1[pl][0];
            float z1 = bb1;
#pragma unroll
            for (int ic4 = 0; ic4 < 16; ++ic4) {
                const float4 v = row1[ic4];
                z1 = fmaf(w1sm[ch * 65 + 4 * ic4 + 0], v.x, z1);
                z1 = fmaf(w1sm[ch * 65 + 4 * ic4 + 1], v.y, z1);
                z1 = fmaf(w1sm[ch * 65 + 4 * ic4 + 2], v.z, z1);
                z1 = fmaf(w1sm[ch * 65 + 4 * ic4 + 3], v.w, z1);
            }
            inb2[pl][ch] = fmaxf(fmaf(z1, sc1, sh1), 0.f);
        } else {
            const float z1 = __bfloat162float(Z2[(size_t)p * 64 + ch]);
            inb2[pl][ch] = fmaxf(fmaf(z1, sc1, sh1), 0.f);
        }
        __syncthreads();

#pragma unroll
        for (int q = 0; q < 2; ++q) {
            const int pr = q * 2 + p2;
            const float4* row2 = (const float4*)&inb2[pr][0];
            float z2 = bb2;
#pragma unroll
            for (int ic4 = 0; ic4 < 16; ++ic4) {
                const float4 v = row2[ic4];
                z2 = fmaf(wreg[4 * ic4 + 0], v.x, z2);
                z2 = fmaf(wreg[4 * ic4 + 1], v.y, z2);
                z2 = fmaf(wreg[4 * ic4 + 2], v.z, z2);
                z2 = fmaf(wreg[4 * ic4 + 3], v.w, z2);
            }
            sl += z2; sq += z2 * z2;
            mx = fmaxf(mx, z2); mnv = fminf(mnv, z2);
        }
        if ((t & 7) == 7) {                 // 32-sample group complete
            pmax[p2][c2] = mx; pmin[p2][c2] = mnv;
            __syncthreads();
            if (p2 == 0) {
                const int bm = (base >> 5) + (t >> 3);
                Z3max[(size_t)bm * 128 + c2] = fmaxf(pmax[0][c2], pmax[1][c2]);
                Z3min[(size_t)bm * 128 + c2] = fminf(pmin[0][c2], pmin[1][c2]);
            }
            mx = -FLT_MAX; mnv = FLT_MAX;
        }
        __syncthreads();
    }

    red[tid] = sl; red[256 + tid] = sq;
    __syncthreads();
    if (tid < 128) {
        atomicAdd(&stats_out[tid],       red[tid] + red[128 + tid]);
        atomicAdd(&stats_out[128 + tid], red[256 + tid] + red[256 + 128 + tid]);
    }
}

// ---------------------------------------------------------------------------
// K7: epilogue — BN2+ReLU on the selected z3 extreme, transposed write.
// max_s relu(sc*z+sh) == relu(sc*(sc>0?maxz:minz)+sh)  (bit-exact).
// ---------------------------------------------------------------------------
__global__ __launch_bounds__(256) void pool_mm_kernel(
        const float* __restrict__ Z3max, const float* __restrict__ Z3min,
        const float* __restrict__ stats,
        const float* __restrict__ g, const float* __restrict__ beta,
        float* __restrict__ outNP) {
    const int tid = threadIdx.x;
    const int mtile = blockIdx.x;    // 0..31
    const int b = blockIdx.y;        // 0..15
    const int ch = tid & 127, mh = tid >> 7;

    const float mean  = stats[ch] * INV_NTOT;
    const float var   = stats[128 + ch] * INV_NTOT - mean * mean;
    const float scale = g[ch] * rsqrtf(var + BN_EPS);
    const float shift = beta[ch] - mean * scale;

    __shared__ float pool[32][129];

    for (int pass = 0; pass < 16; ++pass) {
        const int ml = pass * 2 + mh;
        const size_t bm = (size_t)b * NPOINT + mtile * 32 + ml;
        const float zx = Z3max[bm * 128 + ch];
        const float zn = Z3min[bm * 128 + ch];
        const float zsel = (scale >= 0.f) ? zx : zn;
        pool[ml][ch] = fmaxf(fmaf(zsel, scale, shift), 0.f);
    }
    __syncthreads();

#pragma unroll
    for (int r = 0; r < 16; ++r) {
        const int o  = r * 256 + tid;
        const int ml = o & 31;
        const int c2 = o >> 5;
        outNP[((size_t)b * 128 + c2) * NPOINT + mtile * 32 + ml] = pool[ml][c2];
    }
}

// ---------------------------------------------------------------------------
// K6/K7 legacy (tier C fallback, round-5 verbatim): conv2 double pass.
// ---------------------------------------------------------------------------
template<bool RECOMP, bool FINAL>
__global__ __launch_bounds__(256) void conv2_kernel(
        const float* __restrict__ xyz, const float* __restrict__ new_xyz,
        const int* __restrict__ idx, const float* __restrict__ P1,
        const float* __restrict__ w0, const float* __restrict__ b0,
        const float* __restrict__ stats1,
        const float* __restrict__ g0, const float* __restrict__ be0,
        const float* __restrict__ w1, const float* __restrict__ b1,
        const __hip_bfloat16* __restrict__ Z2,
        const float* __restrict__ stats2,
        const float* __restrict__ g1, const float* __restrict__ be1,
        const float* __restrict__ w2, const float* __restrict__ b2,
        const float* __restrict__ stats3,
        const float* __restrict__ g2, const float* __restrict__ be2,
        float* __restrict__ stats_out, float* __restrict__ outNP) {
    const int tid = threadIdx.x;
    const int ch = tid & 63,  pl = tid >> 6;
    const int c2 = tid & 127, p2 = tid >> 7;

    __shared__ float w2sm[128 * 65];
    __shared__ float w1sm[RECOMP ? 64 * 65 : 1];
    __shared__ float inb1[RECOMP ? 4 : 1][65];
    __shared__ float inb2[4][65];
    __shared__ float dls[4][4];
    __shared__ float red[FINAL ? 1 : 512];
    __shared__ float pmax[FINAL ? 2 : 1][128];
    __shared__ float poolbuf[FINAL ? 8 : 1][129];

    for (int t = tid; t < 128 * 64; t += 256)
        w2sm[(t >> 6) * 65 + (t & 63)] = w2[t];
    if (RECOMP)
        for (int t = tid; t < 64 * 64; t += 256)
            w1sm[(t >> 6) * 65 + (t & 63)] = w1[t];

    float wx0 = 0.f, wx1 = 0.f, wx2 = 0.f, bb0 = 0.f, sc0 = 0.f, sh0 = 0.f, bb1 = 0.f;
    if (RECOMP) {
        wx0 = w0[ch * 67 + 0]; wx1 = w0[ch * 67 + 1]; wx2 = w0[ch * 67 + 2];
        bb0 = b0[ch];
        const float mn = stats1[ch] * INV_NTOT;
        const float vr = stats1[64 + ch] * INV_NTOT - mn * mn;
        sc0 = g0[ch] * rsqrtf(vr + BN_EPS);
        sh0 = be0[ch] - mn * sc0;
        bb1 = b1[ch];
    }
    float sc1, sh1;
    {
        const float mn = stats2[ch] * INV_NTOT;
        const float vr = stats2[64 + ch] * INV_NTOT - mn * mn;
        sc1 = g1[ch] * rsqrtf(vr + BN_EPS);
        sh1 = be1[ch] - mn * sc1;
    }
    const float bb2 = b2[c2];
    float sc2 = 0.f, sh2 = 0.f;
    if (FINAL) {
        const float mn = stats3[c2] * INV_NTOT;
        const float vr = stats3[128 + c2] * INV_NTOT - mn * mn;
        sc2 = g2[c2] * rsqrtf(vr + BN_EPS);
        sh2 = be2[c2] - mn * sc2;
    }
    float sl = 0.f, sq = 0.f, mx = -FLT_MAX;
    __syncthreads();

    const int base = blockIdx.x * 256;
    for (int t = 0; t < 64; ++t) {
        const int p = base + t * 4 + pl;
        if (RECOMP) {
            const int i = idx[p];
            const int bm = p >> 5;
            const int b  = bm >> 10;
            if (ch < 3)
                dls[pl][ch] = xyz[(((size_t)(b << 12)) + i) * 3 + ch]
                            - new_xyz[(size_t)bm * 3 + ch];
            __syncthreads();
            const float z0 = z0_calc(P1[(((size_t)(b << 12)) + i) * 64 + ch], bb0,
                                     wx0, wx1, wx2, dls[pl][0], dls[pl][1], dls[pl][2]);
            inb1[pl][ch] = fmaxf(fmaf(z0, sc0, sh0), 0.f);
            __syncthreads();
            float z1 = bb1;
#pragma unroll
            for (int ic = 0; ic < 64; ++ic)
                z1 = fmaf(w1sm[ch * 65 + ic], inb1[pl][ic], z1);
            inb2[pl][ch] = fmaxf(fmaf(z1, sc1, sh1), 0.f);
        } else {
            const float z1 = __bfloat162float(Z2[(size_t)p * 64 + ch]);
            inb2[pl][ch] = fmaxf(fmaf(z1, sc1, sh1), 0.f);
        }
        __syncthreads();

#pragma unroll
        for (int q = 0; q < 2; ++q) {
            const int pr = q * 2 + p2;
            float z2 = bb2;
#pragma unroll
            for (int ic = 0; ic < 64; ++ic)
                z2 = fmaf(w2sm[c2 * 65 + ic], inb2[pr][ic], z2);
            if (FINAL) {
                mx = fmaxf(mx, fmaxf(fmaf(z2, sc2, sh2), 0.f));
            } else {
                sl += z2; sq += z2 * z2;
            }
        }
        if (FINAL && ((t & 7) == 7)) {
            pmax[p2][c2] = mx;
            __syncthreads();
            if (p2 == 0)
                poolbuf[t >> 3][c2] = fmaxf(pmax[0][c2], pmax[1][c2]);
            mx = -FLT_MAX;
        }
        __syncthreads();
    }

    if (FINAL) {
        const int b  = base >> 15;
        const int m0 = (base >> 5) & 1023;
#pragma unroll
        for (int r = 0; r < 4; ++r) {
            const int o   = r * 256 + tid;
            const int row = o >> 3;
            const int gg  = o & 7;
            outNP[((size_t)(b * 128 + row)) * 1024 + m0 + gg] = poolbuf[gg][row];
        }
    } else {
        red[tid] = sl; red[256 + tid] = sq;
        __syncthreads();
        if (tid < 128) {
            atomicAdd(&stats_out[tid],       red[tid] + red[128 + tid]);
            atomicAdd(&stats_out[128 + tid], red[256 + tid] + red[256 + 128 + tid]);
        }
    }
}

// ---------------------------------------------------------------------------
extern "C" void kernel_launch(void* const* d_in, const int* in_sizes, int n_in,
                              void* d_out, int out_size, void* d_ws, size_t ws_size,
                              hipStream_t stream) {
    const float* xyz    = (const float*)d_in[0];
    const float* points = (const float*)d_in[1];
    const float* w0  = (const float*)d_in[2];
    const float* b0  = (const float*)d_in[3];
    const float* g0  = (const float*)d_in[4];
    const float* be0 = (const float*)d_in[5];
    const float* w1  = (const float*)d_in[6];
    const float* b1  = (const float*)d_in[7];
    const float* g1  = (const float*)d_in[8];
    const float* be1 = (const float*)d_in[9];
    const float* w2  = (const float*)d_in[10];
    const float* b2  = (const float*)d_in[11];
    const float* g2  = (const float*)d_in[12];
    const float* be2 = (const float*)d_in[13];

    float* out        = (float*)d_out;
    float* new_xyz    = out;
    float* new_points = out + (size_t)BATCH * NPOINT * 3;

    // ws: idx 2MB | stats 4KB | P1 16MB | Z3max 8MB | Z3min 8MB | Z2 64MB
    char* ws = (char*)d_ws;
    int*   idx   = (int*)ws;
    float* stats = (float*)(ws + (size_t)(2u << 20));
    float* P1    = (float*)(ws + (size_t)(2u << 20) + 4096);
    const size_t offMM = (size_t)(2u << 20) + 4096 + (size_t)BATCH * NPTS * 64 * 4;
    float* Z3max = (float*)(ws + offMM);
    float* Z3min = Z3max + (size_t)BATCH * NPOINT * 128;
    const size_t offZ2 = offMM + (size_t)BATCH * NPOINT * 128 * 4 * 2;
    __hip_bfloat16* Z2 = (__hip_bfloat16*)(ws + offZ2);

    const bool tierA = ws_size >= offZ2 + (size_t)NTOT * 64 * 2;  // ~98 MB
    const bool tierB = ws_size >= offZ2;                          // ~34 MB

    float* stats1 = stats;
    float* stats2 = stats + 128;
    float* stats3 = stats + 256;

    init_stats_kernel<<<1, 512, 0, stream>>>(stats);
    p1_kernel<<<BATCH * NPTS / 256, 256, 0, stream>>>(points, w0, P1);
    fps_kernel<<<BATCH, 512, 0, stream>>>(xyz, new_xyz);
    knn_kernel<<<dim3(NPOINT, BATCH), 256, 0, stream>>>(xyz, new_xyz, idx);
    stats0_kernel<<<NTOT / 256, 256, 0, stream>>>(xyz, new_xyz, idx, P1,
                                                  w0, b0, stats1);
    if (tierA) {
        conv1_kernel<true><<<NTOT / 256, 256, 0, stream>>>(
            xyz, new_xyz, idx, P1, w0, b0, stats1, g0, be0, w1, b1, Z2, stats2);
        conv2s_kernel<false><<<NTOT / 256, 256, 0, stream>>>(
            xyz, new_xyz, idx, P1, w0, b0, stats1, g0, be0, w1, b1, Z2,
            stats2, g1, be1, w2, b2, stats3, Z3max, Z3min);
        pool_mm_kernel<<<dim3(32, BATCH), 256, 0, stream>>>(
            Z3max, Z3min, stats3, g2, be2, new_points);
    } else if (tierB) {
        conv1_kernel<false><<<NTOT / 256, 256, 0, stream>>>(
            xyz, new_xyz, idx, P1, w0, b0, stats1, g0, be0, w1, b1, Z2, stats2);
        conv2s_kernel<true><<<NTOT / 256, 256, 0, stream>>>(
            xyz, new_xyz, idx, P1, w0, b0, stats1, g0, be0, w1, b1, Z2,
            stats2, g1, be1, w2, b2, stats3, Z3max, Z3min);
        pool_mm_kernel<<<dim3(32, BATCH), 256, 0, stream>>>(
            Z3max, Z3min, stats3, g2, be2, new_points);
    } else {
        conv1_kernel<false><<<NTOT / 256, 256, 0, stream>>>(
            xyz, new_xyz, idx, P1, w0, b0, stats1, g0, be0, w1, b1, Z2, stats2);
        conv2_kernel<true, false><<<NTOT / 256, 256, 0, stream>>>(
            xyz, new_xyz, idx, P1, w0, b0, stats1, g0, be0, w1, b1, Z2,
            stats2, g1, be1, w2, b2, stats3, g2, be2, stats3, new_points);
        conv2_kernel<true, true><<<NTOT / 256, 256, 0, stream>>>(
            xyz, new_xyz, idx, P1, w0, b0, stats1, g0, be0, w1, b1, Z2,
            stats2, g1, be1, w2, b2, stats3, g2, be2, stats3, new_points);
    }
}